// Round 14
// baseline (509.716 us; speedup 1.0000x reference)
//
#include <hip/hip_runtime.h>
#include <math.h>

// Problem constants (from setup_inputs)
#define BATCH 256
#define NQ 30
#define NK 100
#define HID 512
#define WORD 300
#define KIN 900          // WORD*3
#define KP 928           // KIN padded to multiple of 32
#define NTIN 29          // KP/32 ksteps
#define NANS 32000
#define NOUT 300
#define NOUTP 384        // NOUT padded (MFMA K for sim)
#define NTG 12           // NOUTP/32
#define NLAYERS 3
#define MQT (BATCH * NQ)   // 7680
#define MKT (BATCH * NK)   // 25600
#define SCALE 0.044194173824159216f  // 1/sqrt(512)
#define KTLD 520           // kt LDS row stride (512 + 8 pad)

typedef __attribute__((ext_vector_type(8))) short bf16x8;
typedef __attribute__((ext_vector_type(4))) float f32x4;
typedef unsigned short ushort_t;

__device__ __forceinline__ unsigned short f2bf(float f) {
  unsigned int u = __float_as_uint(f);
  u = (u + 0x7FFF + ((u >> 16) & 1)) >> 16;  // RNE
  return (unsigned short)u;
}
__device__ __forceinline__ float bf2f(unsigned short s) {
  return __uint_as_float(((unsigned int)s) << 16);
}

typedef const __attribute__((address_space(1))) unsigned int* gas_u32;
typedef __attribute__((address_space(3))) unsigned int* las_u32;
__device__ __forceinline__ void gld_lds16(const void* g, void* l) {
  __builtin_amdgcn_global_load_lds((gas_u32)g, (las_u32)l, 16, 0, 0);
}

// bijective XCD swizzle (m204)
__device__ __forceinline__ int xcd_swz_linear() {
  const int nwg = gridDim.x * gridDim.y;
  const int orig = blockIdx.y * gridDim.x + blockIdx.x;
  const int q = nwg >> 3, r = nwg & 7;
  const int xcd = orig & 7, idx = orig >> 3;
  return (xcd < r ? xcd * (q + 1) : r * (q + 1) + (xcd - r) * q) + idx;
}

// ---------------- reduction helpers ----------------
__device__ __forceinline__ float waveReduceSum(float v) {
#pragma unroll
  for (int o = 32; o > 0; o >>= 1) v += __shfl_xor(v, o);
  return v;
}
__device__ float blockReduceSum512(float v) {
  __shared__ float sm[8];
  int lane = threadIdx.x & 63, w = threadIdx.x >> 6;
  v = waveReduceSum(v);
  if (lane == 0) sm[w] = v;
  __syncthreads();
  float r = 0.f;
#pragma unroll
  for (int i = 0; i < 8; ++i) r += sm[i];
  __syncthreads();
  return r;
}

// ---------------- bf16 MFMA GEMM v4: 2-phase dbuf + swizzled-global opt ----
// SWZA/SWZB: operand stored pre-swizzled [panel][kstep][chunk16x32] so every
// gld_lds16 is a contiguous 1KB wave read (coalescing fix for strided rows).
// zsA/zsB/zsC: element strides per blockIdx.z (batched M-GEMM).
template <int SWZA, int SWZB, int BIAS, int OUTF32, int OUTBF16, int ZC0, int RELU>
__global__ __launch_bounds__(256) void mfma_gemm2(
    const ushort_t* __restrict__ A1, const ushort_t* __restrict__ Bt1,
    const float* __restrict__ bias1, float* __restrict__ C1,
    ushort_t* __restrict__ Cb1, int M1b,
    const ushort_t* __restrict__ A2, const ushort_t* __restrict__ Bt2,
    const float* __restrict__ bias2, float* __restrict__ C2,
    ushort_t* __restrict__ Cb2,
    size_t zsA, size_t zsB, size_t zsC,
    int N, int K, int nbias) {
  __shared__ __align__(16) ushort_t Abuf[2][128 * 32];
  __shared__ __align__(16) ushort_t Bbuf[2][128 * 32];
  const int wg = xcd_swz_linear();
  const int bx = wg % gridDim.x, by = wg / gridDim.x;
  const int z = blockIdx.z;
  const bool sel = (by >= M1b);
  const ushort_t* A = (sel ? A2 : A1) + z * zsA;
  const ushort_t* Bt = (sel ? Bt2 : Bt1) + z * zsB;
  const float* bias = sel ? bias2 : bias1;
  float* C = (sel ? C2 : C1);
  ushort_t* Cb = (sel ? Cb2 : Cb1);
  if (C) C += z * zsC;
  if (Cb) Cb += z * zsC;
  const int row0 = (sel ? (by - M1b) : by) * 128;
  const int col0 = bx * 128;

  const int tid = threadIdx.x;
  const int lane = tid & 63, w = tid >> 6;
  const int wr = w >> 1, wc = w & 1;
  const int s_r = lane & 15, s_kq = lane >> 4;
  const int nt = K / 32;

  // linear-layout source offsets
  const size_t a_lin0 = (size_t)(row0 + (w * 2 + 0) * 16 + s_r) * K + s_kq * 8;
  const size_t a_lin1 = (size_t)(row0 + (w * 2 + 1) * 16 + s_r) * K + s_kq * 8;
  const size_t b_lin0 = (size_t)(col0 + (w * 2 + 0) * 16 + s_r) * K + s_kq * 8;
  const size_t b_lin1 = (size_t)(col0 + (w * 2 + 1) * 16 + s_r) * K + s_kq * 8;
  // swizzled-layout source offsets (contiguous per chunk)
  const size_t a_swz0 = ((size_t)(row0 >> 7) * nt) * 4096 + (w * 2 + 0) * 512 + lane * 8;
  const size_t a_swz1 = a_swz0 + 512;
  const size_t b_swz0 = ((size_t)(col0 >> 7) * nt) * 4096 + (w * 2 + 0) * 512 + lane * 8;
  const size_t b_swz1 = b_swz0 + 512;

  auto stageAB = [&](int t, int bsel) {
    if (SWZA) {
      gld_lds16(A + a_swz0 + (size_t)t * 4096, Abuf[bsel] + (w * 2 + 0) * 512);
      gld_lds16(A + a_swz1 + (size_t)t * 4096, Abuf[bsel] + (w * 2 + 1) * 512);
    } else {
      gld_lds16(A + a_lin0 + t * 32, Abuf[bsel] + (w * 2 + 0) * 512);
      gld_lds16(A + a_lin1 + t * 32, Abuf[bsel] + (w * 2 + 1) * 512);
    }
    if (SWZB) {
      gld_lds16(Bt + b_swz0 + (size_t)t * 4096, Bbuf[bsel] + (w * 2 + 0) * 512);
      gld_lds16(Bt + b_swz1 + (size_t)t * 4096, Bbuf[bsel] + (w * 2 + 1) * 512);
    } else {
      gld_lds16(Bt + b_lin0 + t * 32, Bbuf[bsel] + (w * 2 + 0) * 512);
      gld_lds16(Bt + b_lin1 + t * 32, Bbuf[bsel] + (w * 2 + 1) * 512);
    }
  };

  f32x4 acc[4][4];
#pragma unroll
  for (int i = 0; i < 4; ++i)
#pragma unroll
    for (int j = 0; j < 4; ++j) acc[i][j] = (f32x4){0.f, 0.f, 0.f, 0.f};

  stageAB(0, 0);
  __syncthreads();  // tile 0 resident
  for (int t = 0; t < nt; ++t) {
    const int cur = t & 1;
    if (t + 1 < nt) stageAB(t + 1, cur ^ 1);  // async prefetch overlaps MFMA
    bf16x8 af[4], bfr[4];
#pragma unroll
    for (int mi = 0; mi < 4; ++mi)
      af[mi] = *(const bf16x8*)(Abuf[cur] + (wr * 4 + mi) * 512 + lane * 8);
#pragma unroll
    for (int nj = 0; nj < 4; ++nj)
      bfr[nj] = *(const bf16x8*)(Bbuf[cur] + (wc * 4 + nj) * 512 + lane * 8);
#pragma unroll
    for (int mi = 0; mi < 4; ++mi)
#pragma unroll
      for (int nj = 0; nj < 4; ++nj)
        acc[mi][nj] = __builtin_amdgcn_mfma_f32_16x16x32_bf16(
            af[mi], bfr[nj], acc[mi][nj], 0, 0, 0);
    __syncthreads();  // drains prefetch + protects buffer reuse
  }

#pragma unroll
  for (int nj = 0; nj < 4; ++nj) {
    const int n = col0 + wc * 64 + nj * 16 + (lane & 15);
    const float bb = BIAS ? ((n < nbias) ? bias[n] : 0.f) : 0.f;
#pragma unroll
    for (int mi = 0; mi < 4; ++mi) {
      f32x4 v = acc[mi][nj];
#pragma unroll
      for (int r = 0; r < 4; ++r) {
        const int m = row0 + wr * 64 + mi * 16 + (lane >> 4) * 4 + r;
        float val = v[r] + bb;
        if (RELU) val = fmaxf(val, 0.f);
        if (ZC0 && n == 0) val = 0.f;
        if (OUTF32) C[(size_t)m * N + n] = val;
        if (OUTBF16) Cb[(size_t)m * N + n] = f2bf(val);
      }
    }
  }
}

// ---------------- gather: emb rows -> SWIZZLED tile buffers ----------------
// dest elem for (row m, k): panel=m>>7, chunk=(m&127)>>4, rl=m&15
//   off = (panel*NTIN + k/32)*4096 + chunk*512 + ((k&31)>>3)*128 + rl*8 + (k&7)
__global__ __launch_bounds__(256) void gather_all_k(
    const int* __restrict__ qid, const int* __restrict__ kid,
    const float* __restrict__ emb, ushort_t* __restrict__ gq,
    ushort_t* __restrict__ gk) {
  int m = blockIdx.x;
  const int* ids;
  ushort_t* buf;
  if (m < MQT) {
    ids = qid + m * 3;
    buf = gq;
  } else {
    m -= MQT;
    ids = kid + m * 3;
    buf = gk;
  }
  const int t = threadIdx.x;
  if (t >= KP / 4) return;
  const int k = t * 4;
  ushort4 o = make_ushort4(0, 0, 0, 0);
  if (k < KIN) {
    const int node = (k >= 600) ? 2 : ((k >= 300) ? 1 : 0);
    const int off = k - node * 300;
    const int id = ids[node];
    float4 v = *(const float4*)(emb + (size_t)id * 300 + off);
    if (v.x != v.x) v.x = 0.f;
    if (v.y != v.y) v.y = 0.f;
    if (v.z != v.z) v.z = 0.f;
    if (v.w != v.w) v.w = 0.f;
    o = make_ushort4(f2bf(v.x), f2bf(v.y), f2bf(v.z), f2bf(v.w));
  }
  const int panel = m >> 7, chunk = (m & 127) >> 4, rl = m & 15;
  ushort_t* dst = buf + ((size_t)panel * NTIN + (k >> 5)) * 4096 +
                  chunk * 512 + ((k >> 3) & 3) * 128 + rl * 8 + (k & 7);
  *(ushort4*)dst = o;
}

// ---------------- weight swizzle-cast: w[KIN][HID] -> Bt-swizzled bf16 ------
// grid (NTIN, 4, 2); tile = colPanel cp, kstep ts: dest 4096 contiguous elems
__global__ __launch_bounds__(256) void wcast_swz_k(
    const float* __restrict__ q2h_w, const float* __restrict__ k2h_w,
    ushort_t* __restrict__ q2s, ushort_t* __restrict__ k2s) {
  const float* wsrc = blockIdx.z ? k2h_w : q2h_w;
  ushort_t* dst = (blockIdx.z ? k2s : q2s) +
                  ((size_t)blockIdx.y * NTIN + blockIdx.x) * 4096;
  const int ts = blockIdx.x, cp = blockIdx.y;
  for (int g = threadIdx.x; g < 512; g += 256) {
    const int o = g * 8;
    const int chunk = o >> 9, kq = (o >> 7) & 3, rl = (o >> 3) & 15;
    const int col = cp * 128 + chunk * 16 + rl;
    const int kb = ts * 32 + kq * 8;
    ushort_t tmp[8];
#pragma unroll
    for (int j = 0; j < 8; ++j) {
      const int k = kb + j;
      tmp[j] = (k < KIN) ? f2bf(wsrc[(size_t)k * HID + col]) : (ushort_t)0;
    }
    *(ushort4*)(dst + o) = make_ushort4(tmp[0], tmp[1], tmp[2], tmp[3]);
    *(ushort4*)(dst + o + 4) = make_ushort4(tmp[4], tmp[5], tmp[6], tmp[7]);
  }
}

// ---------------- glove swizzle-cast: [NANS][NOUT] f32 -> Bt-swizzled bf16 --
// grid (NTG, 250); panel gp, kstep ts
__global__ __launch_bounds__(256) void gcast_swz_k(
    const float* __restrict__ glove, ushort_t* __restrict__ gs) {
  const int ts = blockIdx.x, gp = blockIdx.y;
  ushort_t* dst = gs + ((size_t)gp * NTG + ts) * 4096;
  for (int g = threadIdx.x; g < 512; g += 256) {
    const int o = g * 8;
    const int chunk = o >> 9, kq = (o >> 7) & 3, rl = (o >> 3) & 15;
    const int row = gp * 128 + chunk * 16 + rl;
    const int kb = ts * 32 + kq * 8;
    ushort_t tmp[8];
    if (kb + 8 <= NOUT) {
      const float* s = glove + (size_t)row * NOUT + kb;
      float2 a0 = *(const float2*)(s + 0);
      float2 a1 = *(const float2*)(s + 2);
      float2 a2 = *(const float2*)(s + 4);
      float2 a3 = *(const float2*)(s + 6);
      tmp[0] = f2bf(a0.x); tmp[1] = f2bf(a0.y);
      tmp[2] = f2bf(a1.x); tmp[3] = f2bf(a1.y);
      tmp[4] = f2bf(a2.x); tmp[5] = f2bf(a2.y);
      tmp[6] = f2bf(a3.x); tmp[7] = f2bf(a3.y);
    } else {
#pragma unroll
      for (int j = 0; j < 8; ++j) {
        const int k = kb + j;
        tmp[j] = (k < NOUT) ? f2bf(glove[(size_t)row * NOUT + k]) : (ushort_t)0;
      }
    }
    *(ushort4*)(dst + o) = make_ushort4(tmp[0], tmp[1], tmp[2], tmp[3]);
    *(ushort4*)(dst + o + 4) = make_ushort4(tmp[4], tmp[5], tmp[6], tmp[7]);
  }
}

// transpose-cast (linear [N][K] bf16), 2 jobs: z=0 p1w, z=1 p2w
__global__ __launch_bounds__(256) void tcast2_k(
    const float* __restrict__ p1w, const float* __restrict__ p2w,
    ushort_t* __restrict__ p1wt, ushort_t* __restrict__ p2wt) {
  const int z = blockIdx.z;
  const float* src;
  ushort_t* dst;
  int R, Cc, Rp, Cp;
  if (z == 0) { src = p1w; dst = p1wt; R = 1024; Cc = HID;  Rp = 1024; Cp = HID; }
  else        { src = p2w; dst = p2wt; R = HID;  Cc = NOUT; Rp = HID;  Cp = NOUTP; }
  const int r0 = blockIdx.y * 32, c0 = blockIdx.x * 32;
  if (r0 >= Rp || c0 >= Cp) return;
  __shared__ float t[32][33];
  const int tx = threadIdx.x & 31, ty = threadIdx.x >> 5;
#pragma unroll
  for (int i = 0; i < 4; ++i) {
    int r = r0 + ty + i * 8, c = c0 + tx;
    t[ty + i * 8][tx] = (r < R && c < Cc) ? src[(size_t)r * Cc + c] : 0.f;
  }
  __syncthreads();
#pragma unroll
  for (int i = 0; i < 4; ++i) {
    int c = c0 + ty + i * 8, r = r0 + tx;
    if (c < Cp && r < Rp) dst[(size_t)c * Rp + r] = f2bf(t[tx][ty + i * 8]);
  }
}

// plain row-cast of Wk[3] and Wq[3] (512x512 each) f32 -> bf16
__global__ __launch_bounds__(128) void castrows_k(
    const float* __restrict__ Wk, const float* __restrict__ Wq,
    ushort_t* __restrict__ Wkr, ushort_t* __restrict__ Wqr) {
  const int idx = blockIdx.x;  // 0..6*512-1
  const int mat = idx >> 9, row = idx & 511;
  const float* src = (mat < 3 ? Wk + (size_t)mat * HID * HID
                              : Wq + (size_t)(mat - 3) * HID * HID) + (size_t)row * HID;
  ushort_t* dst = (mat < 3 ? Wkr + (size_t)mat * HID * HID
                           : Wqr + (size_t)(mat - 3) * HID * HID) + (size_t)row * HID;
  const int k = threadIdx.x * 4;
  float4 v = *(const float4*)(src + k);
  *(ushort4*)(dst + k) = make_ushort4(f2bf(v.x), f2bf(v.y), f2bf(v.z), f2bf(v.w));
}

// ---------------- fused attention v4: LDS-resident kt/qt, 1 block/batch ----
__global__ __launch_bounds__(512) void att_fused_k(
    const ushort_t* __restrict__ Qp, const ushort_t* __restrict__ Ktc,
    const ushort_t* __restrict__ Qc, ushort_t* __restrict__ Kn,
    ushort_t* __restrict__ Qn) {
  const int b = blockIdx.x;
  __shared__ float S_lds[NK][32];
  __shared__ float PqT[NK][32];
  __shared__ __align__(16) ushort_t kts[NK * KTLD];
  __shared__ __align__(16) ushort_t qts[NQ * HID];
  const int tid = threadIdx.x;
  const int w = tid >> 6, lane = tid & 63;
  const ushort_t* ktg = Ktc + (size_t)b * NK * HID;
  const ushort_t* qtg = Qc + (size_t)b * NQ * HID;

  for (int e = tid; e < NK * 64; e += 512) {
    const int r = e >> 6, c16 = e & 63;
    gld_lds16(ktg + (size_t)r * HID + c16 * 8, kts + (size_t)r * KTLD + c16 * 8);
  }
  for (int e = tid; e < NQ * 64; e += 512) {
    const int r = e >> 6, c16 = e & 63;
    gld_lds16(qtg + (size_t)r * HID + c16 * 8, qts + (size_t)r * HID + c16 * 8);
  }
  __syncthreads();

  if (w < 7) {
    const int r = lane & 15, kq = lane >> 4;
    const ushort_t* qpb = Qp + (size_t)b * NQ * HID;
    const int rowA = w * 16 + r;
    const int rowA_c = (rowA < NK) ? rowA : (NK - 1);
    const int qr1 = (16 + r) < NQ ? (16 + r) : NQ - 1;
    f32x4 a0 = {0.f, 0.f, 0.f, 0.f}, a1 = {0.f, 0.f, 0.f, 0.f};
    for (int k0 = 0; k0 < HID; k0 += 32) {
      bf16x8 af = *(const bf16x8*)(kts + (size_t)rowA_c * KTLD + k0 + kq * 8);
      bf16x8 b0 = *(const bf16x8*)(qpb + (size_t)r * HID + k0 + kq * 8);
      bf16x8 b1 = *(const bf16x8*)(qpb + (size_t)qr1 * HID + k0 + kq * 8);
      a0 = __builtin_amdgcn_mfma_f32_16x16x32_bf16(af, b0, a0, 0, 0, 0);
      a1 = __builtin_amdgcn_mfma_f32_16x16x32_bf16(af, b1, a1, 0, 0, 0);
    }
    const int q0 = lane & 15, mb = (lane >> 4) * 4;
#pragma unroll
    for (int rr = 0; rr < 4; ++rr) {
      const int mA = w * 16 + mb + rr;
      if (mA < NK) {
        S_lds[mA][q0] = a0[rr] * SCALE;
        if (q0 + 16 < NQ) S_lds[mA][q0 + 16] = a1[rr] * SCALE;
      }
    }
  }
  __syncthreads();
  if (tid < NQ) {
    const int q = tid;
    float m = -1e30f;
    for (int kr = 0; kr < NK; ++kr) m = fmaxf(m, S_lds[kr][q]);
    float s = 0.f;
    for (int kr = 0; kr < NK; ++kr) {
      float e = expf(S_lds[kr][q] - m);
      PqT[kr][q] = e;
      s += e;
    }
    float inv = 1.f / s;
    for (int kr = 0; kr < NK; ++kr) PqT[kr][q] *= inv;
  } else if (tid >= 32 && tid < 32 + NK) {
    const int kr = tid - 32;
    PqT[kr][30] = 0.f;
    PqT[kr][31] = 0.f;
  }
  __syncthreads();
  if (tid < NK) {
    const int kr = tid;
    float m = -1e30f;
#pragma unroll
    for (int q = 0; q < NQ; ++q) m = fmaxf(m, S_lds[kr][q]);
    float s = 0.f;
    float e[NQ];
#pragma unroll
    for (int q = 0; q < NQ; ++q) {
      e[q] = expf(S_lds[kr][q] - m);
      s += e[q];
    }
    float inv = 1.f / s;
#pragma unroll
    for (int q = 0; q < NQ; ++q) S_lds[kr][q] = e[q] * inv;
    S_lds[kr][30] = 0.f;
    S_lds[kr][31] = 0.f;
  }
  __syncthreads();

  const int c = tid;
  float qx[32], ax[32];
#pragma unroll
  for (int q = 0; q < NQ; ++q) qx[q] = bf2f(qts[q * HID + c]);
  qx[30] = 0.f;
  qx[31] = 0.f;
#pragma unroll
  for (int i = 0; i < 32; ++i) ax[i] = 0.f;
  ushort_t* kout = Kn + (size_t)b * NK * HID;
  for (int kr = 0; kr < NK; ++kr) {
    const float kx = bf2f(kts[(size_t)kr * KTLD + c]);
    float sx = kx;
#pragma unroll
    for (int g = 0; g < 8; ++g) {
      float4 pk = *(const float4*)&S_lds[kr][g * 4];
      sx = fmaf(pk.x, qx[g * 4 + 0], sx);
      sx = fmaf(pk.y, qx[g * 4 + 1], sx);
      sx = fmaf(pk.z, qx[g * 4 + 2], sx);
      sx = fmaf(pk.w, qx[g * 4 + 3], sx);
      float4 pq = *(const float4*)&PqT[kr][g * 4];
      ax[g * 4 + 0] = fmaf(pq.x, kx, ax[g * 4 + 0]);
      ax[g * 4 + 1] = fmaf(pq.y, kx, ax[g * 4 + 1]);
      ax[g * 4 + 2] = fmaf(pq.z, kx, ax[g * 4 + 2]);
      ax[g * 4 + 3] = fmaf(pq.w, kx, ax[g * 4 + 3]);
    }
    kout[(size_t)kr * HID + c] = f2bf(sx);
  }
  ushort_t* qout = Qn + (size_t)b * NQ * HID;
#pragma unroll
  for (int q = 0; q < NQ; ++q)
    qout[(size_t)q * HID + c] = f2bf(ax[q] + qx[q]);
}

// ---------------- fused boundary: parallel row-norms ----------------
__global__ __launch_bounds__(512) void finale_k(
    const ushort_t* __restrict__ Kb, const ushort_t* __restrict__ Qb,
    ushort_t* __restrict__ lastb, const float* __restrict__ curv) {
  const int b = blockIdx.x, tid = threadIdx.x;
  const int w = tid >> 6, lane = tid & 63;
  const float c = curv[NLAYERS];
  const float Kc = 1.f / c, sqrtK = sqrtf(Kc);
  __shared__ float fsc[NK + NQ];
  __shared__ float fst[NK + NQ];
  const ushort_t* xkp = Kb + (size_t)b * NK * HID;
  const ushort_t* xqp = Qb + (size_t)b * NQ * HID;

  for (int r = w; r < NK + NQ; r += 8) {
    const ushort_t* row =
        (r < NK) ? (xkp + (size_t)r * HID) : (xqp + (size_t)(r - NK) * HID);
    bf16x8 v = *(const bf16x8*)(row + lane * 8);
    float ss = 0.f;
#pragma unroll
    for (int j = 0; j < 8; ++j) {
      float t = bf2f((unsigned short)v[j]);
      ss = fmaf(t, t, ss);
    }
    ss = waveReduceSum(ss);
    if (lane == 0) {
      float n = fmaxf(sqrtf(ss), 1e-15f);
      float f = sqrtK * sinhf(n / sqrtK) / n;
      fsc[r] = f;
      fst[r] = sqrtf(fmaxf(Kc + f * f * ss, 1e-7f));
    }
  }
  __syncthreads();

  float mk, mq;
  if (tid == 0) {
    float sk = 0.f, sq2 = 0.f;
    for (int r = 0; r < NK; ++r) sk += fst[r];
    for (int r = 0; r < NQ; ++r) sq2 += fst[NK + r];
    mk = sk;
    mq = sq2;
  } else {
    float sk = 0.f, sq2 = 0.f;
    for (int r = 0; r < NK; ++r)
      sk = fmaf(fsc[r], bf2f(xkp[(size_t)r * HID + tid]), sk);
    for (int r = 0; r < NQ; ++r)
      sq2 = fmaf(fsc[NK + r], bf2f(xqp[(size_t)r * HID + tid]), sq2);
    mk = sk;
    mq = sq2;
  }
  mk *= (1.f / NK);
  mq *= (1.f / NQ);

  float sq = ((tid == 0) ? 0.f : mk * mk) + mq * mq;
  float ssall = blockReduceSum512(sq);
  __shared__ float x0sh;
  if (tid == 0) x0sh = mk;
  __syncthreads();
  const float x0 = x0sh;
  const float n = fmaxf(sqrtf(ssall), 1e-15f);
  const float theta = fmaxf(x0 / sqrtK, 1.f + 1e-7f);
  const float rr = sqrtK * acoshf(theta) / n;
  ushort_t* ob = lastb + (size_t)b * 1024;
  ob[tid] = (tid == 0) ? (ushort_t)0 : f2bf(rr * mk);
  ob[512 + tid] = f2bf(rr * mq);
}

// ---------------- tail: 2-pass online log-softmax ----------------
__global__ __launch_bounds__(512) void logsoftmax_k(float* __restrict__ x) {
  const int b = blockIdx.x, tid = threadIdx.x;
  float4* row = (float4*)(x + (size_t)b * NANS);
  float m = -3.4e38f, s = 0.f;
  for (int i = tid; i < NANS / 4; i += 512) {
    float4 v = row[i];
    float lm = fmaxf(fmaxf(v.x, v.y), fmaxf(v.z, v.w));
    float nm = fmaxf(m, lm);
    s = s * expf(m - nm) + expf(v.x - nm) + expf(v.y - nm) +
        expf(v.z - nm) + expf(v.w - nm);
    m = nm;
  }
#pragma unroll
  for (int o = 32; o > 0; o >>= 1) {
    float mo = __shfl_xor(m, o);
    float so = __shfl_xor(s, o);
    float nm = fmaxf(m, mo);
    s = s * expf(m - nm) + so * expf(mo - nm);
    m = nm;
  }
  __shared__ float smm[8], sms[8];
  const int w = tid >> 6, lane = tid & 63;
  if (lane == 0) { smm[w] = m; sms[w] = s; }
  __syncthreads();
  float gm = smm[0], gs = sms[0];
#pragma unroll
  for (int i = 1; i < 8; ++i) {
    float nm = fmaxf(gm, smm[i]);
    gs = gs * expf(gm - nm) + sms[i] * expf(smm[i] - nm);
    gm = nm;
  }
  const float lse = gm + logf(gs);
  for (int i = tid; i < NANS / 4; i += 512) {
    float4 v = row[i];
    v.x -= lse; v.y -= lse; v.z -= lse; v.w -= lse;
    row[i] = v;
  }
}

// ---------------- launch ----------------
extern "C" void kernel_launch(void* const* d_in, const int* in_sizes, int n_in,
                              void* d_out, int out_size, void* d_ws, size_t ws_size,
                              hipStream_t stream) {
  const int* qid = (const int*)d_in[0];
  const int* kid = (const int*)d_in[1];
  const float* emb = (const float*)d_in[2];
  const float* q2h_w = (const float*)d_in[3];
  const float* q2h_b = (const float*)d_in[4];
  const float* k2h_w = (const float*)d_in[5];
  const float* k2h_b = (const float*)d_in[6];
  const float* Wk = (const float*)d_in[7];
  const float* Wq = (const float*)d_in[8];
  const float* curv = (const float*)d_in[9];
  const float* p1w = (const float*)d_in[10];
  const float* p1b = (const float*)d_in[11];
  const float* p2w = (const float*)d_in[12];
  const float* p2b = (const float*)d_in[13];
  const float* glove = (const float*)d_in[14];
  float* out = (float*)d_out;

  // ---- workspace layout (all bf16) ----
  ushort_t* u = (ushort_t*)d_ws;
  ushort_t* Ks0 = u;                           // 25600*512 (k-state ping)
  ushort_t* Ks1 = Ks0 + (size_t)MKT * HID;     // 25600*512 (k-state pong)
  ushort_t* Qs0 = Ks1 + (size_t)MKT * HID;     // 7680*512
  ushort_t* Qs1 = Qs0 + (size_t)MQT * HID;     // 7680*512
  ushort_t* Qps = Qs1 + (size_t)MQT * HID;     // 7680*512 (qp' scratch)
  ushort_t* gq = Qps + (size_t)MQT * HID;      // 60 panels * NTIN * 4096
  ushort_t* gk = gq + (size_t)(MQT / 128) * NTIN * 4096;  // 200 panels
  ushort_t* q2s = gk + (size_t)(MKT / 128) * NTIN * 4096; // 4*NTIN*4096 swz
  ushort_t* k2s = q2s + (size_t)4 * NTIN * 4096;
  ushort_t* gsw = k2s + (size_t)4 * NTIN * 4096;          // glove swz 250*NTG*4096
  ushort_t* Wkr = gsw + (size_t)250 * NTG * 4096;         // 3*512*512
  ushort_t* Wqr = Wkr + (size_t)NLAYERS * HID * HID;
  ushort_t* Mb = Wqr + (size_t)NLAYERS * HID * HID;       // 3*512*512
  ushort_t* p1wt = Mb + (size_t)NLAYERS * HID * HID;      // 512*1024
  ushort_t* p2wt = p1wt + (size_t)HID * 1024;             // 384*512
  ushort_t* lastb = p2wt + (size_t)NOUTP * HID;           // 256*1024
  ushort_t* h1b = lastb + (size_t)BATCH * 1024;           // 256*512
  ushort_t* o2b = h1b + (size_t)BATCH * HID;              // 256*384

  // ---- pre-casts ----
  gather_all_k<<<MQT + MKT, 256, 0, stream>>>(qid, kid, emb, gq, gk);
  wcast_swz_k<<<dim3(NTIN, 4, 2), 256, 0, stream>>>(q2h_w, k2h_w, q2s, k2s);
  gcast_swz_k<<<dim3(NTG, 250), 256, 0, stream>>>(glove, gsw);
  tcast2_k<<<dim3(16, 32, 2), 256, 0, stream>>>(p1w, p2w, p1wt, p2wt);
  castrows_k<<<6 * HID, 128, 0, stream>>>(Wk, Wq, Wkr, Wqr);

  // ---- M_i = Wk_i @ Wq_i^T (bf16 out), batched over z ----
  mfma_gemm2<0, 0, 0, 0, 1, 0, 0><<<dim3(HID / 128, HID / 128, NLAYERS), 256, 0, stream>>>(
      Wkr, Wqr, nullptr, nullptr, Mb, HID / 128,
      Wkr, Wqr, nullptr, nullptr, Mb,
      (size_t)HID * HID, (size_t)HID * HID, (size_t)HID * HID, HID, HID, HID);

  // ---- input projections (merged q+k), swizzled A+B, fused proj_tan0 ----
  mfma_gemm2<1, 1, 1, 0, 1, 1, 0><<<dim3(HID / 128, MQT / 128 + MKT / 128), 256, 0, stream>>>(
      gq, q2s, q2h_b, nullptr, Qs0, MQT / 128,
      gk, k2s, k2h_b, nullptr, Ks0, 0, 0, 0, HID, KP, HID);

  // ---- layers in tangent space ----
  ushort_t* Kc = Ks0;
  ushort_t* Kn = Ks1;
  ushort_t* Qc = Qs0;
  ushort_t* Qn = Qs1;
  for (int i = 0; i < NLAYERS; ++i) {
    mfma_gemm2<0, 0, 0, 0, 1, 0, 0><<<dim3(HID / 128, MQT / 128), 256, 0, stream>>>(
        Qc, Mb + (size_t)i * HID * HID, nullptr, nullptr, Qps, MQT / 128,
        Qc, Mb + (size_t)i * HID * HID, nullptr, nullptr, Qps,
        0, 0, 0, HID, HID, HID);
    att_fused_k<<<BATCH, 512, 0, stream>>>(Qps, Kc, Qc, Kn, Qn);
    ushort_t* t1 = Kc; Kc = Kn; Kn = t1;
    ushort_t* t2 = Qc; Qc = Qn; Qn = t2;
  }

  // ---- fused boundary (expproj + mean + logmap) -> lastb bf16 ----
  finale_k<<<BATCH, 512, 0, stream>>>(Kc, Qc, lastb, curv);

  // ---- head (all MFMA bf16) ----
  mfma_gemm2<0, 0, 1, 0, 1, 0, 1><<<dim3(HID / 128, BATCH / 128), 256, 0, stream>>>(
      lastb, p1wt, p1b, nullptr, h1b, BATCH / 128,
      lastb, p1wt, p1b, nullptr, h1b, 0, 0, 0, HID, 1024, HID);
  mfma_gemm2<0, 0, 1, 0, 1, 0, 0><<<dim3(NOUTP / 128, BATCH / 128), 256, 0, stream>>>(
      h1b, p2wt, p2b, nullptr, o2b, BATCH / 128,
      h1b, p2wt, p2b, nullptr, o2b, 0, 0, 0, NOUTP, HID, NOUT);
  // sim: B = swizzled glove bf16 (coalesced gld_lds)
  mfma_gemm2<0, 1, 0, 1, 0, 0, 0><<<dim3(NANS / 128, BATCH / 128), 256, 0, stream>>>(
      o2b, gsw, nullptr, out, nullptr, BATCH / 128,
      o2b, gsw, nullptr, out, nullptr, 0, 0, 0, NANS, NOUTP, NANS);
  logsoftmax_k<<<BATCH, 512, 0, stream>>>(out);
}

// Round 15
// 461.908 us; speedup vs baseline: 1.1035x; 1.1035x over previous
//
#include <hip/hip_runtime.h>
#include <math.h>

// Problem constants (from setup_inputs)
#define BATCH 256
#define NQ 30
#define NK 100
#define HID 512
#define WORD 300
#define KIN 900          // WORD*3
#define KP 928           // KIN padded to multiple of 32
#define NANS 32000
#define NOUT 300
#define NOUTP 384        // NOUT padded (MFMA K for sim)
#define NTG 12           // NOUTP/32
#define NLAYERS 3
#define MQT (BATCH * NQ)   // 7680
#define MKT (BATCH * NK)   // 25600
#define SCALE 0.044194173824159216f  // 1/sqrt(512)
#define KTLD 520           // kt LDS row stride (512 + 8 pad)

typedef __attribute__((ext_vector_type(8))) short bf16x8;
typedef __attribute__((ext_vector_type(4))) float f32x4;
typedef unsigned short ushort_t;

__device__ __forceinline__ unsigned short f2bf(float f) {
  unsigned int u = __float_as_uint(f);
  u = (u + 0x7FFF + ((u >> 16) & 1)) >> 16;  // RNE
  return (unsigned short)u;
}
__device__ __forceinline__ float bf2f(unsigned short s) {
  return __uint_as_float(((unsigned int)s) << 16);
}

typedef const __attribute__((address_space(1))) unsigned int* gas_u32;
typedef __attribute__((address_space(3))) unsigned int* las_u32;
__device__ __forceinline__ void gld_lds16(const void* g, void* l) {
  __builtin_amdgcn_global_load_lds((gas_u32)g, (las_u32)l, 16, 0, 0);
}

// bijective XCD swizzle (m204)
__device__ __forceinline__ int xcd_swz_linear() {
  const int nwg = gridDim.x * gridDim.y;
  const int orig = blockIdx.y * gridDim.x + blockIdx.x;
  const int q = nwg >> 3, r = nwg & 7;
  const int xcd = orig & 7, idx = orig >> 3;
  return (xcd < r ? xcd * (q + 1) : r * (q + 1) + (xcd - r) * q) + idx;
}

// ---------------- reduction helpers ----------------
__device__ __forceinline__ float waveReduceSum(float v) {
#pragma unroll
  for (int o = 32; o > 0; o >>= 1) v += __shfl_xor(v, o);
  return v;
}
__device__ float blockReduceSum512(float v) {
  __shared__ float sm[8];
  int lane = threadIdx.x & 63, w = threadIdx.x >> 6;
  v = waveReduceSum(v);
  if (lane == 0) sm[w] = v;
  __syncthreads();
  float r = 0.f;
#pragma unroll
  for (int i = 0; i < 8; ++i) r += sm[i];
  __syncthreads();
  return r;
}

// ---------------- bf16 MFMA GEMM: 2-phase double-buffered (round-12 core) --
// SWZB: B stored pre-swizzled [panel][kstep][chunk16x32] -> contiguous 1KB
// wave reads. zsA/zsB/zsC: element strides per blockIdx.z (batched M-GEMM).
template <int SWZB, int BIAS, int OUTF32, int OUTBF16, int ZC0, int RELU>
__global__ __launch_bounds__(256) void mfma_gemm2(
    const ushort_t* __restrict__ A1, const ushort_t* __restrict__ Bt1,
    const float* __restrict__ bias1, float* __restrict__ C1,
    ushort_t* __restrict__ Cb1, int M1b,
    const ushort_t* __restrict__ A2, const ushort_t* __restrict__ Bt2,
    const float* __restrict__ bias2, float* __restrict__ C2,
    ushort_t* __restrict__ Cb2,
    size_t zsA, size_t zsB, size_t zsC,
    int N, int K, int nbias) {
  __shared__ __align__(16) ushort_t Abuf[2][128 * 32];
  __shared__ __align__(16) ushort_t Bbuf[2][128 * 32];
  const int wg = xcd_swz_linear();
  const int bx = wg % gridDim.x, by = wg / gridDim.x;
  const int z = blockIdx.z;
  const bool sel = (by >= M1b);
  const ushort_t* A = (sel ? A2 : A1) + z * zsA;
  const ushort_t* Bt = (sel ? Bt2 : Bt1) + z * zsB;
  const float* bias = sel ? bias2 : bias1;
  float* C = (sel ? C2 : C1);
  ushort_t* Cb = (sel ? Cb2 : Cb1);
  if (C) C += z * zsC;
  if (Cb) Cb += z * zsC;
  const int row0 = (sel ? (by - M1b) : by) * 128;
  const int col0 = bx * 128;

  const int tid = threadIdx.x;
  const int lane = tid & 63, w = tid >> 6;
  const int wr = w >> 1, wc = w & 1;
  const int s_r = lane & 15, s_kq = lane >> 4;
  const int nt = K / 32;

  const size_t a_src0 = (size_t)(row0 + (w * 2 + 0) * 16 + s_r) * K + s_kq * 8;
  const size_t a_src1 = (size_t)(row0 + (w * 2 + 1) * 16 + s_r) * K + s_kq * 8;
  const size_t b_lin0 = (size_t)(col0 + (w * 2 + 0) * 16 + s_r) * K + s_kq * 8;
  const size_t b_lin1 = (size_t)(col0 + (w * 2 + 1) * 16 + s_r) * K + s_kq * 8;
  const size_t b_swz0 = ((size_t)(col0 >> 7) * nt) * 4096 + (w * 2 + 0) * 512 + lane * 8;
  const size_t b_swz1 = b_swz0 + 512;

  auto stageAB = [&](int t, int bsel) {
    const int k0 = t * 32;
    gld_lds16(A + a_src0 + k0, Abuf[bsel] + (w * 2 + 0) * 512);
    gld_lds16(A + a_src1 + k0, Abuf[bsel] + (w * 2 + 1) * 512);
    if (SWZB) {
      gld_lds16(Bt + b_swz0 + (size_t)t * 4096, Bbuf[bsel] + (w * 2 + 0) * 512);
      gld_lds16(Bt + b_swz1 + (size_t)t * 4096, Bbuf[bsel] + (w * 2 + 1) * 512);
    } else {
      gld_lds16(Bt + b_lin0 + k0, Bbuf[bsel] + (w * 2 + 0) * 512);
      gld_lds16(Bt + b_lin1 + k0, Bbuf[bsel] + (w * 2 + 1) * 512);
    }
  };

  f32x4 acc[4][4];
#pragma unroll
  for (int i = 0; i < 4; ++i)
#pragma unroll
    for (int j = 0; j < 4; ++j) acc[i][j] = (f32x4){0.f, 0.f, 0.f, 0.f};

  stageAB(0, 0);
  __syncthreads();  // tile 0 resident
  for (int t = 0; t < nt; ++t) {
    const int cur = t & 1;
    if (t + 1 < nt) stageAB(t + 1, cur ^ 1);  // async prefetch overlaps MFMA
    bf16x8 af[4], bfr[4];
#pragma unroll
    for (int mi = 0; mi < 4; ++mi)
      af[mi] = *(const bf16x8*)(Abuf[cur] + (wr * 4 + mi) * 512 + lane * 8);
#pragma unroll
    for (int nj = 0; nj < 4; ++nj)
      bfr[nj] = *(const bf16x8*)(Bbuf[cur] + (wc * 4 + nj) * 512 + lane * 8);
#pragma unroll
    for (int mi = 0; mi < 4; ++mi)
#pragma unroll
      for (int nj = 0; nj < 4; ++nj)
        acc[mi][nj] = __builtin_amdgcn_mfma_f32_16x16x32_bf16(
            af[mi], bfr[nj], acc[mi][nj], 0, 0, 0);
    __syncthreads();  // drains prefetch + protects buffer reuse
  }

#pragma unroll
  for (int nj = 0; nj < 4; ++nj) {
    const int n = col0 + wc * 64 + nj * 16 + (lane & 15);
    const float bb = BIAS ? ((n < nbias) ? bias[n] : 0.f) : 0.f;
#pragma unroll
    for (int mi = 0; mi < 4; ++mi) {
      f32x4 v = acc[mi][nj];
#pragma unroll
      for (int r = 0; r < 4; ++r) {
        const int m = row0 + wr * 64 + mi * 16 + (lane >> 4) * 4 + r;
        float val = v[r] + bb;
        if (RELU) val = fmaxf(val, 0.f);
        if (ZC0 && n == 0) val = 0.f;
        if (OUTF32) C[(size_t)m * N + n] = val;
        if (OUTBF16) Cb[(size_t)m * N + n] = f2bf(val);
      }
    }
  }
}

// ---------------- pre-cast kernels ----------------
// linear gather: block per row, contiguous reads AND writes
__global__ __launch_bounds__(256) void gather_all_k(
    const int* __restrict__ qid, const int* __restrict__ kid,
    const float* __restrict__ emb, ushort_t* __restrict__ gq,
    ushort_t* __restrict__ gk) {
  int m = blockIdx.x;
  const int* ids;
  ushort_t* outp;
  if (m < MQT) {
    ids = qid + m * 3;
    outp = gq + (size_t)m * KP;
  } else {
    m -= MQT;
    ids = kid + m * 3;
    outp = gk + (size_t)m * KP;
  }
  const int t = threadIdx.x;
  if (t >= KP / 4) return;
  const int k = t * 4;
  ushort4 o = make_ushort4(0, 0, 0, 0);
  if (k < KIN) {
    const int node = (k >= 600) ? 2 : ((k >= 300) ? 1 : 0);
    const int off = k - node * 300;
    const int id = ids[node];
    float4 v = *(const float4*)(emb + (size_t)id * 300 + off);
    if (v.x != v.x) v.x = 0.f;
    if (v.y != v.y) v.y = 0.f;
    if (v.z != v.z) v.z = 0.f;
    if (v.w != v.w) v.w = 0.f;
    o = make_ushort4(f2bf(v.x), f2bf(v.y), f2bf(v.z), f2bf(v.w));
  }
  *(ushort4*)(outp + k) = o;
}

// transpose-cast, 4 jobs: z=0 q2h, z=1 k2h, z=2 p1w, z=3 p2w
__global__ __launch_bounds__(256) void tcast4_k(
    const float* __restrict__ q2h_w, const float* __restrict__ k2h_w,
    const float* __restrict__ p1w, const float* __restrict__ p2w,
    ushort_t* __restrict__ q2h_wt, ushort_t* __restrict__ k2h_wt,
    ushort_t* __restrict__ p1wt, ushort_t* __restrict__ p2wt) {
  const int z = blockIdx.z;
  const float* src;
  ushort_t* dst;
  int R, Cc, Rp, Cp;
  if (z == 0)      { src = q2h_w; dst = q2h_wt; R = KIN;  Cc = HID;  Rp = KP;   Cp = HID; }
  else if (z == 1) { src = k2h_w; dst = k2h_wt; R = KIN;  Cc = HID;  Rp = KP;   Cp = HID; }
  else if (z == 2) { src = p1w; dst = p1wt; R = 1024; Cc = HID;  Rp = 1024; Cp = HID; }
  else             { src = p2w; dst = p2wt; R = HID;  Cc = NOUT; Rp = HID;  Cp = NOUTP; }
  const int r0 = blockIdx.y * 32, c0 = blockIdx.x * 32;
  if (r0 >= Rp || c0 >= Cp) return;
  __shared__ float t[32][33];
  const int tx = threadIdx.x & 31, ty = threadIdx.x >> 5;
#pragma unroll
  for (int i = 0; i < 4; ++i) {
    int r = r0 + ty + i * 8, c = c0 + tx;
    t[ty + i * 8][tx] = (r < R && c < Cc) ? src[(size_t)r * Cc + c] : 0.f;
  }
  __syncthreads();
#pragma unroll
  for (int i = 0; i < 4; ++i) {
    int c = c0 + ty + i * 8, r = r0 + tx;
    if (c < Cp && r < Rp) dst[(size_t)c * Rp + r] = f2bf(t[tx][ty + i * 8]);
  }
}

// glove swizzle-cast: [NANS][NOUT] f32 -> Bt-swizzled bf16 (coalesced writes)
__global__ __launch_bounds__(256) void gcast_swz_k(
    const float* __restrict__ glove, ushort_t* __restrict__ gs) {
  const int ts = blockIdx.x, gp = blockIdx.y;
  ushort_t* dst = gs + ((size_t)gp * NTG + ts) * 4096;
  for (int g = threadIdx.x; g < 512; g += 256) {
    const int o = g * 8;
    const int chunk = o >> 9, kq = (o >> 7) & 3, rl = (o >> 3) & 15;
    const int row = gp * 128 + chunk * 16 + rl;
    const int kb = ts * 32 + kq * 8;
    ushort_t tmp[8];
    if (kb + 8 <= NOUT) {
      const float* s = glove + (size_t)row * NOUT + kb;
      float2 a0 = *(const float2*)(s + 0);
      float2 a1 = *(const float2*)(s + 2);
      float2 a2 = *(const float2*)(s + 4);
      float2 a3 = *(const float2*)(s + 6);
      tmp[0] = f2bf(a0.x); tmp[1] = f2bf(a0.y);
      tmp[2] = f2bf(a1.x); tmp[3] = f2bf(a1.y);
      tmp[4] = f2bf(a2.x); tmp[5] = f2bf(a2.y);
      tmp[6] = f2bf(a3.x); tmp[7] = f2bf(a3.y);
    } else {
#pragma unroll
      for (int j = 0; j < 8; ++j) {
        const int k = kb + j;
        tmp[j] = (k < NOUT) ? f2bf(glove[(size_t)row * NOUT + k]) : (ushort_t)0;
      }
    }
    *(ushort4*)(dst + o) = make_ushort4(tmp[0], tmp[1], tmp[2], tmp[3]);
    *(ushort4*)(dst + o + 4) = make_ushort4(tmp[4], tmp[5], tmp[6], tmp[7]);
  }
}

// plain row-cast of Wk[3] and Wq[3] (512x512 each) f32 -> bf16
__global__ __launch_bounds__(128) void castrows_k(
    const float* __restrict__ Wk, const float* __restrict__ Wq,
    ushort_t* __restrict__ Wkr, ushort_t* __restrict__ Wqr) {
  const int idx = blockIdx.x;  // 0..6*512-1
  const int mat = idx >> 9, row = idx & 511;
  const float* src = (mat < 3 ? Wk + (size_t)mat * HID * HID
                              : Wq + (size_t)(mat - 3) * HID * HID) + (size_t)row * HID;
  ushort_t* dst = (mat < 3 ? Wkr + (size_t)mat * HID * HID
                           : Wqr + (size_t)(mat - 3) * HID * HID) + (size_t)row * HID;
  const int k = threadIdx.x * 4;
  float4 v = *(const float4*)(src + k);
  *(ushort4*)(dst + k) = make_ushort4(f2bf(v.x), f2bf(v.y), f2bf(v.z), f2bf(v.w));
}

// ---------------- fused attention: LDS-resident kt/qt, 1 block/batch ----
__global__ __launch_bounds__(512) void att_fused_k(
    const ushort_t* __restrict__ Qp, const ushort_t* __restrict__ Ktc,
    const ushort_t* __restrict__ Qc, ushort_t* __restrict__ Kn,
    ushort_t* __restrict__ Qn) {
  const int b = blockIdx.x;
  __shared__ float S_lds[NK][32];
  __shared__ float PqT[NK][32];
  __shared__ __align__(16) ushort_t kts[NK * KTLD];
  __shared__ __align__(16) ushort_t qts[NQ * HID];
  const int tid = threadIdx.x;
  const int w = tid >> 6, lane = tid & 63;
  const ushort_t* ktg = Ktc + (size_t)b * NK * HID;
  const ushort_t* qtg = Qc + (size_t)b * NQ * HID;

  for (int e = tid; e < NK * 64; e += 512) {
    const int r = e >> 6, c16 = e & 63;
    gld_lds16(ktg + (size_t)r * HID + c16 * 8, kts + (size_t)r * KTLD + c16 * 8);
  }
  for (int e = tid; e < NQ * 64; e += 512) {
    const int r = e >> 6, c16 = e & 63;
    gld_lds16(qtg + (size_t)r * HID + c16 * 8, qts + (size_t)r * HID + c16 * 8);
  }
  __syncthreads();

  if (w < 7) {
    const int r = lane & 15, kq = lane >> 4;
    const ushort_t* qpb = Qp + (size_t)b * NQ * HID;
    const int rowA = w * 16 + r;
    const int rowA_c = (rowA < NK) ? rowA : (NK - 1);
    const int qr1 = (16 + r) < NQ ? (16 + r) : NQ - 1;
    f32x4 a0 = {0.f, 0.f, 0.f, 0.f}, a1 = {0.f, 0.f, 0.f, 0.f};
    for (int k0 = 0; k0 < HID; k0 += 32) {
      bf16x8 af = *(const bf16x8*)(kts + (size_t)rowA_c * KTLD + k0 + kq * 8);
      bf16x8 b0 = *(const bf16x8*)(qpb + (size_t)r * HID + k0 + kq * 8);
      bf16x8 b1 = *(const bf16x8*)(qpb + (size_t)qr1 * HID + k0 + kq * 8);
      a0 = __builtin_amdgcn_mfma_f32_16x16x32_bf16(af, b0, a0, 0, 0, 0);
      a1 = __builtin_amdgcn_mfma_f32_16x16x32_bf16(af, b1, a1, 0, 0, 0);
    }
    const int q0 = lane & 15, mb = (lane >> 4) * 4;
#pragma unroll
    for (int rr = 0; rr < 4; ++rr) {
      const int mA = w * 16 + mb + rr;
      if (mA < NK) {
        S_lds[mA][q0] = a0[rr] * SCALE;
        if (q0 + 16 < NQ) S_lds[mA][q0 + 16] = a1[rr] * SCALE;
      }
    }
  }
  __syncthreads();
  if (tid < NQ) {
    const int q = tid;
    float m = -1e30f;
    for (int kr = 0; kr < NK; ++kr) m = fmaxf(m, S_lds[kr][q]);
    float s = 0.f;
    for (int kr = 0; kr < NK; ++kr) {
      float e = expf(S_lds[kr][q] - m);
      PqT[kr][q] = e;
      s += e;
    }
    float inv = 1.f / s;
    for (int kr = 0; kr < NK; ++kr) PqT[kr][q] *= inv;
  } else if (tid >= 32 && tid < 32 + NK) {
    const int kr = tid - 32;
    PqT[kr][30] = 0.f;
    PqT[kr][31] = 0.f;
  }
  __syncthreads();
  if (tid < NK) {
    const int kr = tid;
    float m = -1e30f;
#pragma unroll
    for (int q = 0; q < NQ; ++q) m = fmaxf(m, S_lds[kr][q]);
    float s = 0.f;
    float e[NQ];
#pragma unroll
    for (int q = 0; q < NQ; ++q) {
      e[q] = expf(S_lds[kr][q] - m);
      s += e[q];
    }
    float inv = 1.f / s;
#pragma unroll
    for (int q = 0; q < NQ; ++q) S_lds[kr][q] = e[q] * inv;
    S_lds[kr][30] = 0.f;
    S_lds[kr][31] = 0.f;
  }
  __syncthreads();

  const int c = tid;
  float qx[32], ax[32];
#pragma unroll
  for (int q = 0; q < NQ; ++q) qx[q] = bf2f(qts[q * HID + c]);
  qx[30] = 0.f;
  qx[31] = 0.f;
#pragma unroll
  for (int i = 0; i < 32; ++i) ax[i] = 0.f;
  ushort_t* kout = Kn + (size_t)b * NK * HID;
  for (int kr = 0; kr < NK; ++kr) {
    const float kx = bf2f(kts[(size_t)kr * KTLD + c]);
    float sx = kx;
#pragma unroll
    for (int g = 0; g < 8; ++g) {
      float4 pk = *(const float4*)&S_lds[kr][g * 4];
      sx = fmaf(pk.x, qx[g * 4 + 0], sx);
      sx = fmaf(pk.y, qx[g * 4 + 1], sx);
      sx = fmaf(pk.z, qx[g * 4 + 2], sx);
      sx = fmaf(pk.w, qx[g * 4 + 3], sx);
      float4 pq = *(const float4*)&PqT[kr][g * 4];
      ax[g * 4 + 0] = fmaf(pq.x, kx, ax[g * 4 + 0]);
      ax[g * 4 + 1] = fmaf(pq.y, kx, ax[g * 4 + 1]);
      ax[g * 4 + 2] = fmaf(pq.z, kx, ax[g * 4 + 2]);
      ax[g * 4 + 3] = fmaf(pq.w, kx, ax[g * 4 + 3]);
    }
    kout[(size_t)kr * HID + c] = f2bf(sx);
  }
  ushort_t* qout = Qn + (size_t)b * NQ * HID;
#pragma unroll
  for (int q = 0; q < NQ; ++q)
    qout[(size_t)q * HID + c] = f2bf(ax[q] + qx[q]);
}

// ---------------- fused boundary: parallel row-norms ----------------
__global__ __launch_bounds__(512) void finale_k(
    const ushort_t* __restrict__ Kb, const ushort_t* __restrict__ Qb,
    ushort_t* __restrict__ lastb, const float* __restrict__ curv) {
  const int b = blockIdx.x, tid = threadIdx.x;
  const int w = tid >> 6, lane = tid & 63;
  const float c = curv[NLAYERS];
  const float Kc = 1.f / c, sqrtK = sqrtf(Kc);
  __shared__ float fsc[NK + NQ];
  __shared__ float fst[NK + NQ];
  const ushort_t* xkp = Kb + (size_t)b * NK * HID;
  const ushort_t* xqp = Qb + (size_t)b * NQ * HID;

  for (int r = w; r < NK + NQ; r += 8) {
    const ushort_t* row =
        (r < NK) ? (xkp + (size_t)r * HID) : (xqp + (size_t)(r - NK) * HID);
    bf16x8 v = *(const bf16x8*)(row + lane * 8);
    float ss = 0.f;
#pragma unroll
    for (int j = 0; j < 8; ++j) {
      float t = bf2f((unsigned short)v[j]);
      ss = fmaf(t, t, ss);
    }
    ss = waveReduceSum(ss);
    if (lane == 0) {
      float n = fmaxf(sqrtf(ss), 1e-15f);
      float f = sqrtK * sinhf(n / sqrtK) / n;
      fsc[r] = f;
      fst[r] = sqrtf(fmaxf(Kc + f * f * ss, 1e-7f));
    }
  }
  __syncthreads();

  float mk, mq;
  if (tid == 0) {
    float sk = 0.f, sq2 = 0.f;
    for (int r = 0; r < NK; ++r) sk += fst[r];
    for (int r = 0; r < NQ; ++r) sq2 += fst[NK + r];
    mk = sk;
    mq = sq2;
  } else {
    float sk = 0.f, sq2 = 0.f;
    for (int r = 0; r < NK; ++r)
      sk = fmaf(fsc[r], bf2f(xkp[(size_t)r * HID + tid]), sk);
    for (int r = 0; r < NQ; ++r)
      sq2 = fmaf(fsc[NK + r], bf2f(xqp[(size_t)r * HID + tid]), sq2);
    mk = sk;
    mq = sq2;
  }
  mk *= (1.f / NK);
  mq *= (1.f / NQ);

  float sq = ((tid == 0) ? 0.f : mk * mk) + mq * mq;
  float ssall = blockReduceSum512(sq);
  __shared__ float x0sh;
  if (tid == 0) x0sh = mk;
  __syncthreads();
  const float x0 = x0sh;
  const float n = fmaxf(sqrtf(ssall), 1e-15f);
  const float theta = fmaxf(x0 / sqrtK, 1.f + 1e-7f);
  const float rr = sqrtK * acoshf(theta) / n;
  ushort_t* ob = lastb + (size_t)b * 1024;
  ob[tid] = (tid == 0) ? (ushort_t)0 : f2bf(rr * mk);
  ob[512 + tid] = f2bf(rr * mq);
}

// ---------------- tail: 2-pass online log-softmax ----------------
__global__ __launch_bounds__(512) void logsoftmax_k(float* __restrict__ x) {
  const int b = blockIdx.x, tid = threadIdx.x;
  float4* row = (float4*)(x + (size_t)b * NANS);
  float m = -3.4e38f, s = 0.f;
  for (int i = tid; i < NANS / 4; i += 512) {
    float4 v = row[i];
    float lm = fmaxf(fmaxf(v.x, v.y), fmaxf(v.z, v.w));
    float nm = fmaxf(m, lm);
    s = s * expf(m - nm) + expf(v.x - nm) + expf(v.y - nm) +
        expf(v.z - nm) + expf(v.w - nm);
    m = nm;
  }
#pragma unroll
  for (int o = 32; o > 0; o >>= 1) {
    float mo = __shfl_xor(m, o);
    float so = __shfl_xor(s, o);
    float nm = fmaxf(m, mo);
    s = s * expf(m - nm) + so * expf(mo - nm);
    m = nm;
  }
  __shared__ float smm[8], sms[8];
  const int w = tid >> 6, lane = tid & 63;
  if (lane == 0) { smm[w] = m; sms[w] = s; }
  __syncthreads();
  float gm = smm[0], gs = sms[0];
#pragma unroll
  for (int i = 1; i < 8; ++i) {
    float nm = fmaxf(gm, smm[i]);
    gs = gs * expf(gm - nm) + sms[i] * expf(smm[i] - nm);
    gm = nm;
  }
  const float lse = gm + logf(gs);
  for (int i = tid; i < NANS / 4; i += 512) {
    float4 v = row[i];
    v.x -= lse; v.y -= lse; v.z -= lse; v.w -= lse;
    row[i] = v;
  }
}

// ---------------- launch ----------------
extern "C" void kernel_launch(void* const* d_in, const int* in_sizes, int n_in,
                              void* d_out, int out_size, void* d_ws, size_t ws_size,
                              hipStream_t stream) {
  const int* qid = (const int*)d_in[0];
  const int* kid = (const int*)d_in[1];
  const float* emb = (const float*)d_in[2];
  const float* q2h_w = (const float*)d_in[3];
  const float* q2h_b = (const float*)d_in[4];
  const float* k2h_w = (const float*)d_in[5];
  const float* k2h_b = (const float*)d_in[6];
  const float* Wk = (const float*)d_in[7];
  const float* Wq = (const float*)d_in[8];
  const float* curv = (const float*)d_in[9];
  const float* p1w = (const float*)d_in[10];
  const float* p1b = (const float*)d_in[11];
  const float* p2w = (const float*)d_in[12];
  const float* p2b = (const float*)d_in[13];
  const float* glove = (const float*)d_in[14];
  float* out = (float*)d_out;

  // ---- workspace layout (all bf16) ----
  ushort_t* u = (ushort_t*)d_ws;
  ushort_t* Ks0 = u;                           // 25600*512 (k-state ping)
  ushort_t* Ks1 = Ks0 + (size_t)MKT * HID;     // 25600*512 (k-state pong)
  ushort_t* Qs0 = Ks1 + (size_t)MKT * HID;     // 7680*512
  ushort_t* Qs1 = Qs0 + (size_t)MQT * HID;     // 7680*512
  ushort_t* Qps = Qs1 + (size_t)MQT * HID;     // 7680*512 (qp' scratch)
  ushort_t* gq = Qps + (size_t)MQT * HID;      // 7680*928
  ushort_t* gk = gq + (size_t)MQT * KP;        // 25600*928
  ushort_t* q2h_wt = gk + (size_t)MKT * KP;    // [512][928] bf16
  ushort_t* k2h_wt = q2h_wt + (size_t)HID * KP;
  ushort_t* Wkr = k2h_wt + (size_t)HID * KP;   // 3*512*512 (row-major bf16)
  ushort_t* Wqr = Wkr + (size_t)NLAYERS * HID * HID;
  ushort_t* Mb = Wqr + (size_t)NLAYERS * HID * HID;    // 3*512*512 (M=Wk@Wq^T)
  ushort_t* p1wt = Mb + (size_t)NLAYERS * HID * HID;   // 512*1024
  ushort_t* p2wt = p1wt + (size_t)HID * 1024;          // 384*512
  ushort_t* lastb = p2wt + (size_t)NOUTP * HID;        // 256*1024
  ushort_t* h1b = lastb + (size_t)BATCH * 1024;        // 256*512
  ushort_t* o2b = h1b + (size_t)BATCH * HID;           // 256*384
  ushort_t* gsw = o2b + (size_t)BATCH * NOUTP;         // 250*NTG*4096 (glove swz)

  // ---- pre-casts ----
  gather_all_k<<<MQT + MKT, 256, 0, stream>>>(qid, kid, emb, gq, gk);
  tcast4_k<<<dim3(16, 32, 4), 256, 0, stream>>>(
      q2h_w, k2h_w, p1w, p2w, q2h_wt, k2h_wt, p1wt, p2wt);
  castrows_k<<<6 * HID, 128, 0, stream>>>(Wk, Wq, Wkr, Wqr);
  gcast_swz_k<<<dim3(NTG, 250), 256, 0, stream>>>(glove, gsw);

  // ---- M_i = Wk_i @ Wq_i^T (bf16 out), batched over z ----
  mfma_gemm2<0, 0, 0, 1, 0, 0><<<dim3(HID / 128, HID / 128, NLAYERS), 256, 0, stream>>>(
      Wkr, Wqr, nullptr, nullptr, Mb, HID / 128,
      Wkr, Wqr, nullptr, nullptr, Mb,
      (size_t)HID * HID, (size_t)HID * HID, (size_t)HID * HID, HID, HID, HID);

  // ---- input projections (merged q+k), fused proj_tan0, bf16 out ----
  mfma_gemm2<0, 1, 0, 1, 1, 0><<<dim3(HID / 128, MQT / 128 + MKT / 128), 256, 0, stream>>>(
      gq, q2h_wt, q2h_b, nullptr, Qs0, MQT / 128,
      gk, k2h_wt, k2h_b, nullptr, Ks0, 0, 0, 0, HID, KP, HID);

  // ---- layers in tangent space ----
  ushort_t* Kc = Ks0;
  ushort_t* Kn = Ks1;
  ushort_t* Qc = Qs0;
  ushort_t* Qn = Qs1;
  for (int i = 0; i < NLAYERS; ++i) {
    // qp' = qt @ M_i^T -> Qps  (replaces BOTH kp and qp GEMMs)
    mfma_gemm2<0, 0, 0, 1, 0, 0><<<dim3(HID / 128, MQT / 128), 256, 0, stream>>>(
        Qc, Mb + (size_t)i * HID * HID, nullptr, nullptr, Qps, MQT / 128,
        Qc, Mb + (size_t)i * HID * HID, nullptr, nullptr, Qps,
        0, 0, 0, HID, HID, HID);
    // attention: S = kt @ qp'^T, kt/qt LDS-resident
    att_fused_k<<<BATCH, 512, 0, stream>>>(Qps, Kc, Qc, Kn, Qn);
    ushort_t* t1 = Kc; Kc = Kn; Kn = t1;
    ushort_t* t2 = Qc; Qc = Qn; Qn = t2;
  }

  // ---- fused boundary (expproj + mean + logmap) -> lastb bf16 ----
  finale_k<<<BATCH, 512, 0, stream>>>(Kc, Qc, lastb, curv);

  // ---- head (all MFMA bf16) ----
  mfma_gemm2<0, 1, 0, 1, 0, 1><<<dim3(HID / 128, BATCH / 128), 256, 0, stream>>>(
      lastb, p1wt, p1b, nullptr, h1b, BATCH / 128,
      lastb, p1wt, p1b, nullptr, h1b, 0, 0, 0, HID, 1024, HID);
  mfma_gemm2<0, 1, 0, 1, 0, 0><<<dim3(NOUTP / 128, BATCH / 128), 256, 0, stream>>>(
      h1b, p2wt, p2b, nullptr, o2b, BATCH / 128,
      h1b, p2wt, p2b, nullptr, o2b, 0, 0, 0, NOUTP, HID, NOUT);
  // sim: B = swizzled glove bf16 (coalesced producer AND consumer)
  mfma_gemm2<1, 0, 1, 0, 0, 0><<<dim3(NANS / 128, BATCH / 128), 256, 0, stream>>>(
      o2b, gsw, nullptr, out, nullptr, BATCH / 128,
      o2b, gsw, nullptr, out, nullptr, 0, 0, 0, NANS, NOUTP, NANS);
  logsoftmax_k<<<BATCH, 512, 0, stream>>>(out);
}

// Round 16
// 445.863 us; speedup vs baseline: 1.1432x; 1.0360x over previous
//
#include <hip/hip_runtime.h>
#include <math.h>

// Problem constants (from setup_inputs)
#define BATCH 256
#define NQ 30
#define NK 100
#define HID 512
#define WORD 300
#define KIN 900          // WORD*3
#define KP 928           // KIN padded to multiple of 32
#define NANS 32000
#define NOUT 300
#define NOUTP 384        // NOUT padded (MFMA K for sim)
#define NTG 12           // NOUTP/32
#define NLAYERS 3
#define MQT (BATCH * NQ)   // 7680
#define MKT (BATCH * NK)   // 25600
#define SCALE 0.044194173824159216f  // 1/sqrt(512)
#define KTLD 520           // kt LDS row stride (512 + 8 pad)
#define CLDST 136          // C-tile LDS row stride (128 + 8: 16B-aligned rows)

typedef __attribute__((ext_vector_type(8))) short bf16x8;
typedef __attribute__((ext_vector_type(4))) float f32x4;
typedef unsigned short ushort_t;

__device__ __forceinline__ unsigned short f2bf(float f) {
  unsigned int u = __float_as_uint(f);
  u = (u + 0x7FFF + ((u >> 16) & 1)) >> 16;  // RNE
  return (unsigned short)u;
}
__device__ __forceinline__ float bf2f(unsigned short s) {
  return __uint_as_float(((unsigned int)s) << 16);
}

typedef const __attribute__((address_space(1))) unsigned int* gas_u32;
typedef __attribute__((address_space(3))) unsigned int* las_u32;
__device__ __forceinline__ void gld_lds16(const void* g, void* l) {
  __builtin_amdgcn_global_load_lds((gas_u32)g, (las_u32)l, 16, 0, 0);
}

// bijective XCD swizzle (m204)
__device__ __forceinline__ int xcd_swz_linear() {
  const int nwg = gridDim.x * gridDim.y;
  const int orig = blockIdx.y * gridDim.x + blockIdx.x;
  const int q = nwg >> 3, r = nwg & 7;
  const int xcd = orig & 7, idx = orig >> 3;
  return (xcd < r ? xcd * (q + 1) : r * (q + 1) + (xcd - r) * q) + idx;
}

// ---------------- reduction helpers ----------------
__device__ __forceinline__ float waveReduceSum(float v) {
#pragma unroll
  for (int o = 32; o > 0; o >>= 1) v += __shfl_xor(v, o);
  return v;
}
__device__ float blockReduceSum512(float v) {
  __shared__ float sm[8];
  int lane = threadIdx.x & 63, w = threadIdx.x >> 6;
  v = waveReduceSum(v);
  if (lane == 0) sm[w] = v;
  __syncthreads();
  float r = 0.f;
#pragma unroll
  for (int i = 0; i < 8; ++i) r += sm[i];
  __syncthreads();
  return r;
}

// ---------------- bf16 MFMA GEMM: 2-phase dbuf + LDS-staged bf16 epilogue --
// SWZB: B stored pre-swizzled [panel][kstep][chunk16x32] -> contiguous 1KB
// wave reads. OUTBF16 path stages the C-tile in LDS (reusing the staging
// buffers, dead after the K loop) and stores fully-coalesced 256B segments.
// zsA/zsB/zsC: element strides per blockIdx.z (batched M-GEMM).
template <int SWZB, int BIAS, int OUTF32, int OUTBF16, int ZC0, int RELU>
__global__ __launch_bounds__(256) void mfma_gemm2(
    const ushort_t* __restrict__ A1, const ushort_t* __restrict__ Bt1,
    const float* __restrict__ bias1, float* __restrict__ C1,
    ushort_t* __restrict__ Cb1, int M1b,
    const ushort_t* __restrict__ A2, const ushort_t* __restrict__ Bt2,
    const float* __restrict__ bias2, float* __restrict__ C2,
    ushort_t* __restrict__ Cb2,
    size_t zsA, size_t zsB, size_t zsC,
    int N, int K, int nbias) {
  // smem: staging dbuf (32KB) overlaid by the 128x[CLDST] C-tile (34.8KB)
  __shared__ __align__(16) ushort_t smem[128 * CLDST];
  const int wg = xcd_swz_linear();
  const int bx = wg % gridDim.x, by = wg / gridDim.x;
  const int z = blockIdx.z;
  const bool sel = (by >= M1b);
  const ushort_t* A = (sel ? A2 : A1) + z * zsA;
  const ushort_t* Bt = (sel ? Bt2 : Bt1) + z * zsB;
  const float* bias = sel ? bias2 : bias1;
  float* C = (sel ? C2 : C1);
  ushort_t* Cb = (sel ? Cb2 : Cb1);
  if (C) C += z * zsC;
  if (Cb) Cb += z * zsC;
  const int row0 = (sel ? (by - M1b) : by) * 128;
  const int col0 = bx * 128;

  const int tid = threadIdx.x;
  const int lane = tid & 63, w = tid >> 6;
  const int wr = w >> 1, wc = w & 1;
  const int s_r = lane & 15, s_kq = lane >> 4;
  const int nt = K / 32;

  const size_t a_src0 = (size_t)(row0 + (w * 2 + 0) * 16 + s_r) * K + s_kq * 8;
  const size_t a_src1 = (size_t)(row0 + (w * 2 + 1) * 16 + s_r) * K + s_kq * 8;
  const size_t b_lin0 = (size_t)(col0 + (w * 2 + 0) * 16 + s_r) * K + s_kq * 8;
  const size_t b_lin1 = (size_t)(col0 + (w * 2 + 1) * 16 + s_r) * K + s_kq * 8;
  const size_t b_swz0 = ((size_t)(col0 >> 7) * nt) * 4096 + (w * 2 + 0) * 512 + lane * 8;
  const size_t b_swz1 = b_swz0 + 512;

  auto stageAB = [&](int t, int bsel) {
    const int k0 = t * 32;
    ushort_t* Ab = smem + bsel * 4096;
    ushort_t* Bb = smem + 8192 + bsel * 4096;
    gld_lds16(A + a_src0 + k0, Ab + (w * 2 + 0) * 512);
    gld_lds16(A + a_src1 + k0, Ab + (w * 2 + 1) * 512);
    if (SWZB) {
      gld_lds16(Bt + b_swz0 + (size_t)t * 4096, Bb + (w * 2 + 0) * 512);
      gld_lds16(Bt + b_swz1 + (size_t)t * 4096, Bb + (w * 2 + 1) * 512);
    } else {
      gld_lds16(Bt + b_lin0 + k0, Bb + (w * 2 + 0) * 512);
      gld_lds16(Bt + b_lin1 + k0, Bb + (w * 2 + 1) * 512);
    }
  };

  f32x4 acc[4][4];
#pragma unroll
  for (int i = 0; i < 4; ++i)
#pragma unroll
    for (int j = 0; j < 4; ++j) acc[i][j] = (f32x4){0.f, 0.f, 0.f, 0.f};

  stageAB(0, 0);
  __syncthreads();  // tile 0 resident
  for (int t = 0; t < nt; ++t) {
    const int cur = t & 1;
    if (t + 1 < nt) stageAB(t + 1, cur ^ 1);  // async prefetch overlaps MFMA
    const ushort_t* Ab = smem + cur * 4096;
    const ushort_t* Bb = smem + 8192 + cur * 4096;
    bf16x8 af[4], bfr[4];
#pragma unroll
    for (int mi = 0; mi < 4; ++mi)
      af[mi] = *(const bf16x8*)(Ab + (wr * 4 + mi) * 512 + lane * 8);
#pragma unroll
    for (int nj = 0; nj < 4; ++nj)
      bfr[nj] = *(const bf16x8*)(Bb + (wc * 4 + nj) * 512 + lane * 8);
#pragma unroll
    for (int mi = 0; mi < 4; ++mi)
#pragma unroll
      for (int nj = 0; nj < 4; ++nj)
        acc[mi][nj] = __builtin_amdgcn_mfma_f32_16x16x32_bf16(
            af[mi], bfr[nj], acc[mi][nj], 0, 0, 0);
    __syncthreads();  // drains prefetch + protects buffer reuse
  }

  if (OUTBF16) {
    // stage bf16 C-tile in LDS (staging bufs are dead; post-loop barrier done)
#pragma unroll
    for (int nj = 0; nj < 4; ++nj) {
      const int nl = wc * 64 + nj * 16 + (lane & 15);
      const int n = col0 + nl;
      const float bb = BIAS ? ((n < nbias) ? bias[n] : 0.f) : 0.f;
#pragma unroll
      for (int mi = 0; mi < 4; ++mi) {
        f32x4 v = acc[mi][nj];
#pragma unroll
        for (int r = 0; r < 4; ++r) {
          const int ml = wr * 64 + mi * 16 + (lane >> 4) * 4 + r;
          float val = v[r] + bb;
          if (RELU) val = fmaxf(val, 0.f);
          if (ZC0 && n == 0) val = 0.f;
          smem[ml * CLDST + nl] = f2bf(val);
        }
      }
    }
    __syncthreads();
    // coalesced store: 256 threads x 8 iters x 16B; 16 lanes = 256B/row-seg
#pragma unroll
    for (int j = 0; j < 8; ++j) {
      const int e = j * 2048 + tid * 8;
      const int ml = e >> 7, nl = e & 127;
      uint4 v = *(const uint4*)(smem + ml * CLDST + nl);
      *(uint4*)(Cb + (size_t)(row0 + ml) * N + col0 + nl) = v;
    }
  }
  if (OUTF32) {
#pragma unroll
    for (int nj = 0; nj < 4; ++nj) {
      const int n = col0 + wc * 64 + nj * 16 + (lane & 15);
      const float bb = BIAS ? ((n < nbias) ? bias[n] : 0.f) : 0.f;
#pragma unroll
      for (int mi = 0; mi < 4; ++mi) {
        f32x4 v = acc[mi][nj];
#pragma unroll
        for (int r = 0; r < 4; ++r) {
          const int m = row0 + wr * 64 + mi * 16 + (lane >> 4) * 4 + r;
          float val = v[r] + bb;
          if (RELU) val = fmaxf(val, 0.f);
          if (ZC0 && n == 0) val = 0.f;
          C[(size_t)m * N + n] = val;
        }
      }
    }
  }
}

// ---------------- pre-cast kernels ----------------
// linear gather: block per row, contiguous reads AND writes
__global__ __launch_bounds__(256) void gather_all_k(
    const int* __restrict__ qid, const int* __restrict__ kid,
    const float* __restrict__ emb, ushort_t* __restrict__ gq,
    ushort_t* __restrict__ gk) {
  int m = blockIdx.x;
  const int* ids;
  ushort_t* outp;
  if (m < MQT) {
    ids = qid + m * 3;
    outp = gq + (size_t)m * KP;
  } else {
    m -= MQT;
    ids = kid + m * 3;
    outp = gk + (size_t)m * KP;
  }
  const int t = threadIdx.x;
  if (t >= KP / 4) return;
  const int k = t * 4;
  ushort4 o = make_ushort4(0, 0, 0, 0);
  if (k < KIN) {
    const int node = (k >= 600) ? 2 : ((k >= 300) ? 1 : 0);
    const int off = k - node * 300;
    const int id = ids[node];
    float4 v = *(const float4*)(emb + (size_t)id * 300 + off);
    if (v.x != v.x) v.x = 0.f;
    if (v.y != v.y) v.y = 0.f;
    if (v.z != v.z) v.z = 0.f;
    if (v.w != v.w) v.w = 0.f;
    o = make_ushort4(f2bf(v.x), f2bf(v.y), f2bf(v.z), f2bf(v.w));
  }
  *(ushort4*)(outp + k) = o;
}

// transpose-cast, 4 jobs: z=0 q2h, z=1 k2h, z=2 p1w, z=3 p2w
__global__ __launch_bounds__(256) void tcast4_k(
    const float* __restrict__ q2h_w, const float* __restrict__ k2h_w,
    const float* __restrict__ p1w, const float* __restrict__ p2w,
    ushort_t* __restrict__ q2h_wt, ushort_t* __restrict__ k2h_wt,
    ushort_t* __restrict__ p1wt, ushort_t* __restrict__ p2wt) {
  const int z = blockIdx.z;
  const float* src;
  ushort_t* dst;
  int R, Cc, Rp, Cp;
  if (z == 0)      { src = q2h_w; dst = q2h_wt; R = KIN;  Cc = HID;  Rp = KP;   Cp = HID; }
  else if (z == 1) { src = k2h_w; dst = k2h_wt; R = KIN;  Cc = HID;  Rp = KP;   Cp = HID; }
  else if (z == 2) { src = p1w; dst = p1wt; R = 1024; Cc = HID;  Rp = 1024; Cp = HID; }
  else             { src = p2w; dst = p2wt; R = HID;  Cc = NOUT; Rp = HID;  Cp = NOUTP; }
  const int r0 = blockIdx.y * 32, c0 = blockIdx.x * 32;
  if (r0 >= Rp || c0 >= Cp) return;
  __shared__ float t[32][33];
  const int tx = threadIdx.x & 31, ty = threadIdx.x >> 5;
#pragma unroll
  for (int i = 0; i < 4; ++i) {
    int r = r0 + ty + i * 8, c = c0 + tx;
    t[ty + i * 8][tx] = (r < R && c < Cc) ? src[(size_t)r * Cc + c] : 0.f;
  }
  __syncthreads();
#pragma unroll
  for (int i = 0; i < 4; ++i) {
    int c = c0 + ty + i * 8, r = r0 + tx;
    if (c < Cp && r < Rp) dst[(size_t)c * Rp + r] = f2bf(t[tx][ty + i * 8]);
  }
}

// glove swizzle-cast: [NANS][NOUT] f32 -> Bt-swizzled bf16 (coalesced writes)
__global__ __launch_bounds__(256) void gcast_swz_k(
    const float* __restrict__ glove, ushort_t* __restrict__ gs) {
  const int ts = blockIdx.x, gp = blockIdx.y;
  ushort_t* dst = gs + ((size_t)gp * NTG + ts) * 4096;
  for (int g = threadIdx.x; g < 512; g += 256) {
    const int o = g * 8;
    const int chunk = o >> 9, kq = (o >> 7) & 3, rl = (o >> 3) & 15;
    const int row = gp * 128 + chunk * 16 + rl;
    const int kb = ts * 32 + kq * 8;
    ushort_t tmp[8];
    if (kb + 8 <= NOUT) {
      const float* s = glove + (size_t)row * NOUT + kb;
      float2 a0 = *(const float2*)(s + 0);
      float2 a1 = *(const float2*)(s + 2);
      float2 a2 = *(const float2*)(s + 4);
      float2 a3 = *(const float2*)(s + 6);
      tmp[0] = f2bf(a0.x); tmp[1] = f2bf(a0.y);
      tmp[2] = f2bf(a1.x); tmp[3] = f2bf(a1.y);
      tmp[4] = f2bf(a2.x); tmp[5] = f2bf(a2.y);
      tmp[6] = f2bf(a3.x); tmp[7] = f2bf(a3.y);
    } else {
#pragma unroll
      for (int j = 0; j < 8; ++j) {
        const int k = kb + j;
        tmp[j] = (k < NOUT) ? f2bf(glove[(size_t)row * NOUT + k]) : (ushort_t)0;
      }
    }
    *(ushort4*)(dst + o) = make_ushort4(tmp[0], tmp[1], tmp[2], tmp[3]);
    *(ushort4*)(dst + o + 4) = make_ushort4(tmp[4], tmp[5], tmp[6], tmp[7]);
  }
}

// plain row-cast of Wk[3] and Wq[3] (512x512 each) f32 -> bf16
__global__ __launch_bounds__(128) void castrows_k(
    const float* __restrict__ Wk, const float* __restrict__ Wq,
    ushort_t* __restrict__ Wkr, ushort_t* __restrict__ Wqr) {
  const int idx = blockIdx.x;  // 0..6*512-1
  const int mat = idx >> 9, row = idx & 511;
  const float* src = (mat < 3 ? Wk + (size_t)mat * HID * HID
                              : Wq + (size_t)(mat - 3) * HID * HID) + (size_t)row * HID;
  ushort_t* dst = (mat < 3 ? Wkr + (size_t)mat * HID * HID
                           : Wqr + (size_t)(mat - 3) * HID * HID) + (size_t)row * HID;
  const int k = threadIdx.x * 4;
  float4 v = *(const float4*)(src + k);
  *(ushort4*)(dst + k) = make_ushort4(f2bf(v.x), f2bf(v.y), f2bf(v.z), f2bf(v.w));
}

// ---------------- fused attention: LDS-resident kt/qt, 1 block/batch ----
__global__ __launch_bounds__(512) void att_fused_k(
    const ushort_t* __restrict__ Qp, const ushort_t* __restrict__ Ktc,
    const ushort_t* __restrict__ Qc, ushort_t* __restrict__ Kn,
    ushort_t* __restrict__ Qn) {
  const int b = blockIdx.x;
  __shared__ float S_lds[NK][32];
  __shared__ float PqT[NK][32];
  __shared__ __align__(16) ushort_t kts[NK * KTLD];
  __shared__ __align__(16) ushort_t qts[NQ * HID];
  const int tid = threadIdx.x;
  const int w = tid >> 6, lane = tid & 63;
  const ushort_t* ktg = Ktc + (size_t)b * NK * HID;
  const ushort_t* qtg = Qc + (size_t)b * NQ * HID;

  for (int e = tid; e < NK * 64; e += 512) {
    const int r = e >> 6, c16 = e & 63;
    gld_lds16(ktg + (size_t)r * HID + c16 * 8, kts + (size_t)r * KTLD + c16 * 8);
  }
  for (int e = tid; e < NQ * 64; e += 512) {
    const int r = e >> 6, c16 = e & 63;
    gld_lds16(qtg + (size_t)r * HID + c16 * 8, qts + (size_t)r * HID + c16 * 8);
  }
  __syncthreads();

  if (w < 7) {
    const int r = lane & 15, kq = lane >> 4;
    const ushort_t* qpb = Qp + (size_t)b * NQ * HID;
    const int rowA = w * 16 + r;
    const int rowA_c = (rowA < NK) ? rowA : (NK - 1);
    const int qr1 = (16 + r) < NQ ? (16 + r) : NQ - 1;
    f32x4 a0 = {0.f, 0.f, 0.f, 0.f}, a1 = {0.f, 0.f, 0.f, 0.f};
    for (int k0 = 0; k0 < HID; k0 += 32) {
      bf16x8 af = *(const bf16x8*)(kts + (size_t)rowA_c * KTLD + k0 + kq * 8);
      bf16x8 b0 = *(const bf16x8*)(qpb + (size_t)r * HID + k0 + kq * 8);
      bf16x8 b1 = *(const bf16x8*)(qpb + (size_t)qr1 * HID + k0 + kq * 8);
      a0 = __builtin_amdgcn_mfma_f32_16x16x32_bf16(af, b0, a0, 0, 0, 0);
      a1 = __builtin_amdgcn_mfma_f32_16x16x32_bf16(af, b1, a1, 0, 0, 0);
    }
    const int q0 = lane & 15, mb = (lane >> 4) * 4;
#pragma unroll
    for (int rr = 0; rr < 4; ++rr) {
      const int mA = w * 16 + mb + rr;
      if (mA < NK) {
        S_lds[mA][q0] = a0[rr] * SCALE;
        if (q0 + 16 < NQ) S_lds[mA][q0 + 16] = a1[rr] * SCALE;
      }
    }
  }
  __syncthreads();
  if (tid < NQ) {
    const int q = tid;
    float m = -1e30f;
    for (int kr = 0; kr < NK; ++kr) m = fmaxf(m, S_lds[kr][q]);
    float s = 0.f;
    for (int kr = 0; kr < NK; ++kr) {
      float e = expf(S_lds[kr][q] - m);
      PqT[kr][q] = e;
      s += e;
    }
    float inv = 1.f / s;
    for (int kr = 0; kr < NK; ++kr) PqT[kr][q] *= inv;
  } else if (tid >= 32 && tid < 32 + NK) {
    const int kr = tid - 32;
    PqT[kr][30] = 0.f;
    PqT[kr][31] = 0.f;
  }
  __syncthreads();
  if (tid < NK) {
    const int kr = tid;
    float m = -1e30f;
#pragma unroll
    for (int q = 0; q < NQ; ++q) m = fmaxf(m, S_lds[kr][q]);
    float s = 0.f;
    float e[NQ];
#pragma unroll
    for (int q = 0; q < NQ; ++q) {
      e[q] = expf(S_lds[kr][q] - m);
      s += e[q];
    }
    float inv = 1.f / s;
#pragma unroll
    for (int q = 0; q < NQ; ++q) S_lds[kr][q] = e[q] * inv;
    S_lds[kr][30] = 0.f;
    S_lds[kr][31] = 0.f;
  }
  __syncthreads();

  const int c = tid;
  float qx[32], ax[32];
#pragma unroll
  for (int q = 0; q < NQ; ++q) qx[q] = bf2f(qts[q * HID + c]);
  qx[30] = 0.f;
  qx[31] = 0.f;
#pragma unroll
  for (int i = 0; i < 32; ++i) ax[i] = 0.f;
  ushort_t* kout = Kn + (size_t)b * NK * HID;
  for (int kr = 0; kr < NK; ++kr) {
    const float kx = bf2f(kts[(size_t)kr * KTLD + c]);
    float sx = kx;
#pragma unroll
    for (int g = 0; g < 8; ++g) {
      float4 pk = *(const float4*)&S_lds[kr][g * 4];
      sx = fmaf(pk.x, qx[g * 4 + 0], sx);
      sx = fmaf(pk.y, qx[g * 4 + 1], sx);
      sx = fmaf(pk.z, qx[g * 4 + 2], sx);
      sx = fmaf(pk.w, qx[g * 4 + 3], sx);
      float4 pq = *(const float4*)&PqT[kr][g * 4];
      ax[g * 4 + 0] = fmaf(pq.x, kx, ax[g * 4 + 0]);
      ax[g * 4 + 1] = fmaf(pq.y, kx, ax[g * 4 + 1]);
      ax[g * 4 + 2] = fmaf(pq.z, kx, ax[g * 4 + 2]);
      ax[g * 4 + 3] = fmaf(pq.w, kx, ax[g * 4 + 3]);
    }
    kout[(size_t)kr * HID + c] = f2bf(sx);
  }
  ushort_t* qout = Qn + (size_t)b * NQ * HID;
#pragma unroll
  for (int q = 0; q < NQ; ++q)
    qout[(size_t)q * HID + c] = f2bf(ax[q] + qx[q]);
}

// ---------------- fused boundary: parallel row-norms ----------------
__global__ __launch_bounds__(512) void finale_k(
    const ushort_t* __restrict__ Kb, const ushort_t* __restrict__ Qb,
    ushort_t* __restrict__ lastb, const float* __restrict__ curv) {
  const int b = blockIdx.x, tid = threadIdx.x;
  const int w = tid >> 6, lane = tid & 63;
  const float c = curv[NLAYERS];
  const float Kc = 1.f / c, sqrtK = sqrtf(Kc);
  __shared__ float fsc[NK + NQ];
  __shared__ float fst[NK + NQ];
  const ushort_t* xkp = Kb + (size_t)b * NK * HID;
  const ushort_t* xqp = Qb + (size_t)b * NQ * HID;

  for (int r = w; r < NK + NQ; r += 8) {
    const ushort_t* row =
        (r < NK) ? (xkp + (size_t)r * HID) : (xqp + (size_t)(r - NK) * HID);
    bf16x8 v = *(const bf16x8*)(row + lane * 8);
    float ss = 0.f;
#pragma unroll
    for (int j = 0; j < 8; ++j) {
      float t = bf2f((unsigned short)v[j]);
      ss = fmaf(t, t, ss);
    }
    ss = waveReduceSum(ss);
    if (lane == 0) {
      float n = fmaxf(sqrtf(ss), 1e-15f);
      float f = sqrtK * sinhf(n / sqrtK) / n;
      fsc[r] = f;
      fst[r] = sqrtf(fmaxf(Kc + f * f * ss, 1e-7f));
    }
  }
  __syncthreads();

  float mk, mq;
  if (tid == 0) {
    float sk = 0.f, sq2 = 0.f;
    for (int r = 0; r < NK; ++r) sk += fst[r];
    for (int r = 0; r < NQ; ++r) sq2 += fst[NK + r];
    mk = sk;
    mq = sq2;
  } else {
    float sk = 0.f, sq2 = 0.f;
    for (int r = 0; r < NK; ++r)
      sk = fmaf(fsc[r], bf2f(xkp[(size_t)r * HID + tid]), sk);
    for (int r = 0; r < NQ; ++r)
      sq2 = fmaf(fsc[NK + r], bf2f(xqp[(size_t)r * HID + tid]), sq2);
    mk = sk;
    mq = sq2;
  }
  mk *= (1.f / NK);
  mq *= (1.f / NQ);

  float sq = ((tid == 0) ? 0.f : mk * mk) + mq * mq;
  float ssall = blockReduceSum512(sq);
  __shared__ float x0sh;
  if (tid == 0) x0sh = mk;
  __syncthreads();
  const float x0 = x0sh;
  const float n = fmaxf(sqrtf(ssall), 1e-15f);
  const float theta = fmaxf(x0 / sqrtK, 1.f + 1e-7f);
  const float rr = sqrtK * acoshf(theta) / n;
  ushort_t* ob = lastb + (size_t)b * 1024;
  ob[tid] = (tid == 0) ? (ushort_t)0 : f2bf(rr * mk);
  ob[512 + tid] = f2bf(rr * mq);
}

// ---------------- tail: 2-pass online log-softmax ----------------
__global__ __launch_bounds__(512) void logsoftmax_k(float* __restrict__ x) {
  const int b = blockIdx.x, tid = threadIdx.x;
  float4* row = (float4*)(x + (size_t)b * NANS);
  float m = -3.4e38f, s = 0.f;
  for (int i = tid; i < NANS / 4; i += 512) {
    float4 v = row[i];
    float lm = fmaxf(fmaxf(v.x, v.y), fmaxf(v.z, v.w));
    float nm = fmaxf(m, lm);
    s = s * expf(m - nm) + expf(v.x - nm) + expf(v.y - nm) +
        expf(v.z - nm) + expf(v.w - nm);
    m = nm;
  }
#pragma unroll
  for (int o = 32; o > 0; o >>= 1) {
    float mo = __shfl_xor(m, o);
    float so = __shfl_xor(s, o);
    float nm = fmaxf(m, mo);
    s = s * expf(m - nm) + so * expf(mo - nm);
    m = nm;
  }
  __shared__ float smm[8], sms[8];
  const int w = tid >> 6, lane = tid & 63;
  if (lane == 0) { smm[w] = m; sms[w] = s; }
  __syncthreads();
  float gm = smm[0], gs = sms[0];
#pragma unroll
  for (int i = 1; i < 8; ++i) {
    float nm = fmaxf(gm, smm[i]);
    gs = gs * expf(gm - nm) + sms[i] * expf(smm[i] - nm);
    gm = nm;
  }
  const float lse = gm + logf(gs);
  for (int i = tid; i < NANS / 4; i += 512) {
    float4 v = row[i];
    v.x -= lse; v.y -= lse; v.z -= lse; v.w -= lse;
    row[i] = v;
  }
}

// ---------------- launch ----------------
extern "C" void kernel_launch(void* const* d_in, const int* in_sizes, int n_in,
                              void* d_out, int out_size, void* d_ws, size_t ws_size,
                              hipStream_t stream) {
  const int* qid = (const int*)d_in[0];
  const int* kid = (const int*)d_in[1];
  const float* emb = (const float*)d_in[2];
  const float* q2h_w = (const float*)d_in[3];
  const float* q2h_b = (const float*)d_in[4];
  const float* k2h_w = (const float*)d_in[5];
  const float* k2h_b = (const float*)d_in[6];
  const float* Wk = (const float*)d_in[7];
  const float* Wq = (const float*)d_in[8];
  const float* curv = (const float*)d_in[9];
  const float* p1w = (const float*)d_in[10];
  const float* p1b = (const float*)d_in[11];
  const float* p2w = (const float*)d_in[12];
  const float* p2b = (const float*)d_in[13];
  const float* glove = (const float*)d_in[14];
  float* out = (float*)d_out;

  // ---- workspace layout (all bf16) ----
  ushort_t* u = (ushort_t*)d_ws;
  ushort_t* Ks0 = u;                           // 25600*512 (k-state ping)
  ushort_t* Ks1 = Ks0 + (size_t)MKT * HID;     // 25600*512 (k-state pong)
  ushort_t* Qs0 = Ks1 + (size_t)MKT * HID;     // 7680*512
  ushort_t* Qs1 = Qs0 + (size_t)MQT * HID;     // 7680*512
  ushort_t* Qps = Qs1 + (size_t)MQT * HID;     // 7680*512 (qp' scratch)
  ushort_t* gq = Qps + (size_t)MQT * HID;      // 7680*928
  ushort_t* gk = gq + (size_t)MQT * KP;        // 25600*928
  ushort_t* q2h_wt = gk + (size_t)MKT * KP;    // [512][928] bf16
  ushort_t* k2h_wt = q2h_wt + (size_t)HID * KP;
  ushort_t* Wkr = k2h_wt + (size_t)HID * KP;   // 3*512*512 (row-major bf16)
  ushort_t* Wqr = Wkr + (size_t)NLAYERS * HID * HID;
  ushort_t* Mb = Wqr + (size_t)NLAYERS * HID * HID;    // 3*512*512 (M=Wk@Wq^T)
  ushort_t* p1wt = Mb + (size_t)NLAYERS * HID * HID;   // 512*1024
  ushort_t* p2wt = p1wt + (size_t)HID * 1024;          // 384*512
  ushort_t* lastb = p2wt + (size_t)NOUTP * HID;        // 256*1024
  ushort_t* h1b = lastb + (size_t)BATCH * 1024;        // 256*512
  ushort_t* o2b = h1b + (size_t)BATCH * HID;           // 256*384
  ushort_t* gsw = o2b + (size_t)BATCH * NOUTP;         // 250*NTG*4096 (glove swz)

  // ---- pre-casts ----
  gather_all_k<<<MQT + MKT, 256, 0, stream>>>(qid, kid, emb, gq, gk);
  tcast4_k<<<dim3(16, 32, 4), 256, 0, stream>>>(
      q2h_w, k2h_w, p1w, p2w, q2h_wt, k2h_wt, p1wt, p2wt);
  castrows_k<<<6 * HID, 128, 0, stream>>>(Wk, Wq, Wkr, Wqr);
  gcast_swz_k<<<dim3(NTG, 250), 256, 0, stream>>>(glove, gsw);

  // ---- M_i = Wk_i @ Wq_i^T (bf16 out), batched over z ----
  mfma_gemm2<0, 0, 0, 1, 0, 0><<<dim3(HID / 128, HID / 128, NLAYERS), 256, 0, stream>>>(
      Wkr, Wqr, nullptr, nullptr, Mb, HID / 128,
      Wkr, Wqr, nullptr, nullptr, Mb,
      (size_t)HID * HID, (size_t)HID * HID, (size_t)HID * HID, HID, HID, HID);

  // ---- input projections (merged q+k), fused proj_tan0, bf16 out ----
  mfma_gemm2<0, 1, 0, 1, 1, 0><<<dim3(HID / 128, MQT / 128 + MKT / 128), 256, 0, stream>>>(
      gq, q2h_wt, q2h_b, nullptr, Qs0, MQT / 128,
      gk, k2h_wt, k2h_b, nullptr, Ks0, 0, 0, 0, HID, KP, HID);

  // ---- layers in tangent space ----
  ushort_t* Kc = Ks0;
  ushort_t* Kn = Ks1;
  ushort_t* Qc = Qs0;
  ushort_t* Qn = Qs1;
  for (int i = 0; i < NLAYERS; ++i) {
    // qp' = qt @ M_i^T -> Qps  (replaces BOTH kp and qp GEMMs)
    mfma_gemm2<0, 0, 0, 1, 0, 0><<<dim3(HID / 128, MQT / 128), 256, 0, stream>>>(
        Qc, Mb + (size_t)i * HID * HID, nullptr, nullptr, Qps, MQT / 128,
        Qc, Mb + (size_t)i * HID * HID, nullptr, nullptr, Qps,
        0, 0, 0, HID, HID, HID);
    // attention: S = kt @ qp'^T, kt/qt LDS-resident
    att_fused_k<<<BATCH, 512, 0, stream>>>(Qps, Kc, Qc, Kn, Qn);
    ushort_t* t1 = Kc; Kc = Kn; Kn = t1;
    ushort_t* t2 = Qc; Qc = Qn; Qn = t2;
  }

  // ---- fused boundary (expproj + mean + logmap) -> lastb bf16 ----
  finale_k<<<BATCH, 512, 0, stream>>>(Kc, Qc, lastb, curv);

  // ---- head (all MFMA bf16) ----
  mfma_gemm2<0, 1, 0, 1, 0, 1><<<dim3(HID / 128, BATCH / 128), 256, 0, stream>>>(
      lastb, p1wt, p1b, nullptr, h1b, BATCH / 128,
      lastb, p1wt, p1b, nullptr, h1b, 0, 0, 0, HID, 1024, HID);
  mfma_gemm2<0, 1, 0, 1, 0, 0><<<dim3(NOUTP / 128, BATCH / 128), 256, 0, stream>>>(
      h1b, p2wt, p2b, nullptr, o2b, BATCH / 128,
      h1b, p2wt, p2b, nullptr, o2b, 0, 0, 0, NOUTP, HID, NOUT);
  // sim: B = swizzled glove bf16 (coalesced producer AND consumer)
  mfma_gemm2<1, 0, 1, 0, 0, 0><<<dim3(NANS / 128, BATCH / 128), 256, 0, stream>>>(
      o2b, gsw, nullptr, out, nullptr, BATCH / 128,
      o2b, gsw, nullptr, out, nullptr, 0, 0, 0, NANS, NOUTP, NANS);
  logsoftmax_k<<<BATCH, 512, 0, stream>>>(out);
}

// Round 17
// 402.239 us; speedup vs baseline: 1.2672x; 1.1085x over previous
//
#include <hip/hip_runtime.h>
#include <math.h>

// Problem constants (from setup_inputs)
#define BATCH 256
#define NQ 30
#define NK 100
#define HID 512
#define WORD 300
#define KIN 900          // WORD*3
#define KP 928           // KIN padded to multiple of 32
#define NANS 32000
#define NOUT 300
#define NOUTP 384        // NOUT padded (MFMA K for sim)
#define NTG 12           // NOUTP/32
#define NLAYERS 3
#define MQT (BATCH * NQ)   // 7680
#define MKT (BATCH * NK)   // 25600
#define SCALE 0.044194173824159216f  // 1/sqrt(512)
#define KTLD 520           // kt LDS row stride (512 + 8 pad)
#define CLDST 136          // C-tile LDS row stride (128 + 8: 16B-aligned rows)
#define SST 36             // S LDS row stride (floats); Pk overlay stride 72 u16
#define PQLD 136           // Pq row stride (u16)

typedef __attribute__((ext_vector_type(8))) short bf16x8;
typedef __attribute__((ext_vector_type(4))) float f32x4;
typedef unsigned short ushort_t;

__device__ __forceinline__ unsigned short f2bf(float f) {
  unsigned int u = __float_as_uint(f);
  u = (u + 0x7FFF + ((u >> 16) & 1)) >> 16;  // RNE
  return (unsigned short)u;
}
__device__ __forceinline__ float bf2f(unsigned short s) {
  return __uint_as_float(((unsigned int)s) << 16);
}

typedef const __attribute__((address_space(1))) unsigned int* gas_u32;
typedef __attribute__((address_space(3))) unsigned int* las_u32;
__device__ __forceinline__ void gld_lds16(const void* g, void* l) {
  __builtin_amdgcn_global_load_lds((gas_u32)g, (las_u32)l, 16, 0, 0);
}

// bijective XCD swizzle (m204)
__device__ __forceinline__ int xcd_swz_linear() {
  const int nwg = gridDim.x * gridDim.y;
  const int orig = blockIdx.y * gridDim.x + blockIdx.x;
  const int q = nwg >> 3, r = nwg & 7;
  const int xcd = orig & 7, idx = orig >> 3;
  return (xcd < r ? xcd * (q + 1) : r * (q + 1) + (xcd - r) * q) + idx;
}

// ---------------- reduction helpers ----------------
__device__ __forceinline__ float waveReduceSum(float v) {
#pragma unroll
  for (int o = 32; o > 0; o >>= 1) v += __shfl_xor(v, o);
  return v;
}
__device__ float blockReduceSum512(float v) {
  __shared__ float sm[8];
  int lane = threadIdx.x & 63, w = threadIdx.x >> 6;
  v = waveReduceSum(v);
  if (lane == 0) sm[w] = v;
  __syncthreads();
  float r = 0.f;
#pragma unroll
  for (int i = 0; i < 8; ++i) r += sm[i];
  __syncthreads();
  return r;
}

// ---------------- bf16 MFMA GEMM: 2-phase dbuf + LDS-staged bf16 epilogue --
template <int SWZB, int BIAS, int OUTF32, int OUTBF16, int ZC0, int RELU>
__global__ __launch_bounds__(256) void mfma_gemm2(
    const ushort_t* __restrict__ A1, const ushort_t* __restrict__ Bt1,
    const float* __restrict__ bias1, float* __restrict__ C1,
    ushort_t* __restrict__ Cb1, int M1b,
    const ushort_t* __restrict__ A2, const ushort_t* __restrict__ Bt2,
    const float* __restrict__ bias2, float* __restrict__ C2,
    ushort_t* __restrict__ Cb2,
    size_t zsA, size_t zsB, size_t zsC,
    int N, int K, int nbias) {
  __shared__ __align__(16) ushort_t smem[128 * CLDST];
  const int wg = xcd_swz_linear();
  const int bx = wg % gridDim.x, by = wg / gridDim.x;
  const int z = blockIdx.z;
  const bool sel = (by >= M1b);
  const ushort_t* A = (sel ? A2 : A1) + z * zsA;
  const ushort_t* Bt = (sel ? Bt2 : Bt1) + z * zsB;
  const float* bias = sel ? bias2 : bias1;
  float* C = (sel ? C2 : C1);
  ushort_t* Cb = (sel ? Cb2 : Cb1);
  if (C) C += z * zsC;
  if (Cb) Cb += z * zsC;
  const int row0 = (sel ? (by - M1b) : by) * 128;
  const int col0 = bx * 128;

  const int tid = threadIdx.x;
  const int lane = tid & 63, w = tid >> 6;
  const int wr = w >> 1, wc = w & 1;
  const int s_r = lane & 15, s_kq = lane >> 4;
  const int nt = K / 32;

  const size_t a_src0 = (size_t)(row0 + (w * 2 + 0) * 16 + s_r) * K + s_kq * 8;
  const size_t a_src1 = (size_t)(row0 + (w * 2 + 1) * 16 + s_r) * K + s_kq * 8;
  const size_t b_lin0 = (size_t)(col0 + (w * 2 + 0) * 16 + s_r) * K + s_kq * 8;
  const size_t b_lin1 = (size_t)(col0 + (w * 2 + 1) * 16 + s_r) * K + s_kq * 8;
  const size_t b_swz0 = ((size_t)(col0 >> 7) * nt) * 4096 + (w * 2 + 0) * 512 + lane * 8;
  const size_t b_swz1 = b_swz0 + 512;

  auto stageAB = [&](int t, int bsel) {
    const int k0 = t * 32;
    ushort_t* Ab = smem + bsel * 4096;
    ushort_t* Bb = smem + 8192 + bsel * 4096;
    gld_lds16(A + a_src0 + k0, Ab + (w * 2 + 0) * 512);
    gld_lds16(A + a_src1 + k0, Ab + (w * 2 + 1) * 512);
    if (SWZB) {
      gld_lds16(Bt + b_swz0 + (size_t)t * 4096, Bb + (w * 2 + 0) * 512);
      gld_lds16(Bt + b_swz1 + (size_t)t * 4096, Bb + (w * 2 + 1) * 512);
    } else {
      gld_lds16(Bt + b_lin0 + k0, Bb + (w * 2 + 0) * 512);
      gld_lds16(Bt + b_lin1 + k0, Bb + (w * 2 + 1) * 512);
    }
  };

  f32x4 acc[4][4];
#pragma unroll
  for (int i = 0; i < 4; ++i)
#pragma unroll
    for (int j = 0; j < 4; ++j) acc[i][j] = (f32x4){0.f, 0.f, 0.f, 0.f};

  stageAB(0, 0);
  __syncthreads();
  for (int t = 0; t < nt; ++t) {
    const int cur = t & 1;
    if (t + 1 < nt) stageAB(t + 1, cur ^ 1);
    const ushort_t* Ab = smem + cur * 4096;
    const ushort_t* Bb = smem + 8192 + cur * 4096;
    bf16x8 af[4], bfr[4];
#pragma unroll
    for (int mi = 0; mi < 4; ++mi)
      af[mi] = *(const bf16x8*)(Ab + (wr * 4 + mi) * 512 + lane * 8);
#pragma unroll
    for (int nj = 0; nj < 4; ++nj)
      bfr[nj] = *(const bf16x8*)(Bb + (wc * 4 + nj) * 512 + lane * 8);
#pragma unroll
    for (int mi = 0; mi < 4; ++mi)
#pragma unroll
      for (int nj = 0; nj < 4; ++nj)
        acc[mi][nj] = __builtin_amdgcn_mfma_f32_16x16x32_bf16(
            af[mi], bfr[nj], acc[mi][nj], 0, 0, 0);
    __syncthreads();
  }

  if (OUTBF16) {
#pragma unroll
    for (int nj = 0; nj < 4; ++nj) {
      const int nl = wc * 64 + nj * 16 + (lane & 15);
      const int n = col0 + nl;
      const float bb = BIAS ? ((n < nbias) ? bias[n] : 0.f) : 0.f;
#pragma unroll
      for (int mi = 0; mi < 4; ++mi) {
        f32x4 v = acc[mi][nj];
#pragma unroll
        for (int r = 0; r < 4; ++r) {
          const int ml = wr * 64 + mi * 16 + (lane >> 4) * 4 + r;
          float val = v[r] + bb;
          if (RELU) val = fmaxf(val, 0.f);
          if (ZC0 && n == 0) val = 0.f;
          smem[ml * CLDST + nl] = f2bf(val);
        }
      }
    }
    __syncthreads();
#pragma unroll
    for (int j = 0; j < 8; ++j) {
      const int e = j * 2048 + tid * 8;
      const int ml = e >> 7, nl = e & 127;
      uint4 v = *(const uint4*)(smem + ml * CLDST + nl);
      *(uint4*)(Cb + (size_t)(row0 + ml) * N + col0 + nl) = v;
    }
  }
  if (OUTF32) {
#pragma unroll
    for (int nj = 0; nj < 4; ++nj) {
      const int n = col0 + wc * 64 + nj * 16 + (lane & 15);
      const float bb = BIAS ? ((n < nbias) ? bias[n] : 0.f) : 0.f;
#pragma unroll
      for (int mi = 0; mi < 4; ++mi) {
        f32x4 v = acc[mi][nj];
#pragma unroll
        for (int r = 0; r < 4; ++r) {
          const int m = row0 + wr * 64 + mi * 16 + (lane >> 4) * 4 + r;
          float val = v[r] + bb;
          if (RELU) val = fmaxf(val, 0.f);
          if (ZC0 && n == 0) val = 0.f;
          C[(size_t)m * N + n] = val;
        }
      }
    }
  }
}

// ---------------- pre-cast kernels ----------------
__global__ __launch_bounds__(256) void gather_all_k(
    const int* __restrict__ qid, const int* __restrict__ kid,
    const float* __restrict__ emb, ushort_t* __restrict__ gq,
    ushort_t* __restrict__ gk) {
  int m = blockIdx.x;
  const int* ids;
  ushort_t* outp;
  if (m < MQT) {
    ids = qid + m * 3;
    outp = gq + (size_t)m * KP;
  } else {
    m -= MQT;
    ids = kid + m * 3;
    outp = gk + (size_t)m * KP;
  }
  const int t = threadIdx.x;
  if (t >= KP / 4) return;
  const int k = t * 4;
  ushort4 o = make_ushort4(0, 0, 0, 0);
  if (k < KIN) {
    const int node = (k >= 600) ? 2 : ((k >= 300) ? 1 : 0);
    const int off = k - node * 300;
    const int id = ids[node];
    float4 v = *(const float4*)(emb + (size_t)id * 300 + off);
    if (v.x != v.x) v.x = 0.f;
    if (v.y != v.y) v.y = 0.f;
    if (v.z != v.z) v.z = 0.f;
    if (v.w != v.w) v.w = 0.f;
    o = make_ushort4(f2bf(v.x), f2bf(v.y), f2bf(v.z), f2bf(v.w));
  }
  *(ushort4*)(outp + k) = o;
}

__global__ __launch_bounds__(256) void tcast4_k(
    const float* __restrict__ q2h_w, const float* __restrict__ k2h_w,
    const float* __restrict__ p1w, const float* __restrict__ p2w,
    ushort_t* __restrict__ q2h_wt, ushort_t* __restrict__ k2h_wt,
    ushort_t* __restrict__ p1wt, ushort_t* __restrict__ p2wt) {
  const int z = blockIdx.z;
  const float* src;
  ushort_t* dst;
  int R, Cc, Rp, Cp;
  if (z == 0)      { src = q2h_w; dst = q2h_wt; R = KIN;  Cc = HID;  Rp = KP;   Cp = HID; }
  else if (z == 1) { src = k2h_w; dst = k2h_wt; R = KIN;  Cc = HID;  Rp = KP;   Cp = HID; }
  else if (z == 2) { src = p1w; dst = p1wt; R = 1024; Cc = HID;  Rp = 1024; Cp = HID; }
  else             { src = p2w; dst = p2wt; R = HID;  Cc = NOUT; Rp = HID;  Cp = NOUTP; }
  const int r0 = blockIdx.y * 32, c0 = blockIdx.x * 32;
  if (r0 >= Rp || c0 >= Cp) return;
  __shared__ float t[32][33];
  const int tx = threadIdx.x & 31, ty = threadIdx.x >> 5;
#pragma unroll
  for (int i = 0; i < 4; ++i) {
    int r = r0 + ty + i * 8, c = c0 + tx;
    t[ty + i * 8][tx] = (r < R && c < Cc) ? src[(size_t)r * Cc + c] : 0.f;
  }
  __syncthreads();
#pragma unroll
  for (int i = 0; i < 4; ++i) {
    int c = c0 + ty + i * 8, r = r0 + tx;
    if (c < Cp && r < Rp) dst[(size_t)c * Rp + r] = f2bf(t[tx][ty + i * 8]);
  }
}

__global__ __launch_bounds__(256) void gcast_swz_k(
    const float* __restrict__ glove, ushort_t* __restrict__ gs) {
  const int ts = blockIdx.x, gp = blockIdx.y;
  ushort_t* dst = gs + ((size_t)gp * NTG + ts) * 4096;
  for (int g = threadIdx.x; g < 512; g += 256) {
    const int o = g * 8;
    const int chunk = o >> 9, kq = (o >> 7) & 3, rl = (o >> 3) & 15;
    const int row = gp * 128 + chunk * 16 + rl;
    const int kb = ts * 32 + kq * 8;
    ushort_t tmp[8];
    if (kb + 8 <= NOUT) {
      const float* s = glove + (size_t)row * NOUT + kb;
      float2 a0 = *(const float2*)(s + 0);
      float2 a1 = *(const float2*)(s + 2);
      float2 a2 = *(const float2*)(s + 4);
      float2 a3 = *(const float2*)(s + 6);
      tmp[0] = f2bf(a0.x); tmp[1] = f2bf(a0.y);
      tmp[2] = f2bf(a1.x); tmp[3] = f2bf(a1.y);
      tmp[4] = f2bf(a2.x); tmp[5] = f2bf(a2.y);
      tmp[6] = f2bf(a3.x); tmp[7] = f2bf(a3.y);
    } else {
#pragma unroll
      for (int j = 0; j < 8; ++j) {
        const int k = kb + j;
        tmp[j] = (k < NOUT) ? f2bf(glove[(size_t)row * NOUT + k]) : (ushort_t)0;
      }
    }
    *(ushort4*)(dst + o) = make_ushort4(tmp[0], tmp[1], tmp[2], tmp[3]);
    *(ushort4*)(dst + o + 4) = make_ushort4(tmp[4], tmp[5], tmp[6], tmp[7]);
  }
}

__global__ __launch_bounds__(128) void castrows_k(
    const float* __restrict__ Wk, const float* __restrict__ Wq,
    ushort_t* __restrict__ Wkr, ushort_t* __restrict__ Wqr) {
  const int idx = blockIdx.x;
  const int mat = idx >> 9, row = idx & 511;
  const float* src = (mat < 3 ? Wk + (size_t)mat * HID * HID
                              : Wq + (size_t)(mat - 3) * HID * HID) + (size_t)row * HID;
  ushort_t* dst = (mat < 3 ? Wkr + (size_t)mat * HID * HID
                           : Wqr + (size_t)(mat - 3) * HID * HID) + (size_t)row * HID;
  const int k = threadIdx.x * 4;
  float4 v = *(const float4*)(src + k);
  *(ushort4*)(dst + k) = make_ushort4(f2bf(v.x), f2bf(v.y), f2bf(v.z), f2bf(v.w));
}

// ---------------- fused attention v5: MFMA phases 3/4 ----------------
// LDS: S (f32, stride SST; Pk bf16 overlay stride 72 u16) + Pq bf16 + kt + qt
// phase1: S = SCALE*kt@qp'^T (MFMA); 2a: Pq rows bf16; 2b: Pk rows (overlay)
// phase3: att_k = Pk@qt + kt (MFMA, K=32); phase4: att_q = Pq@kt + qt (K=128)
__global__ __launch_bounds__(512) void att_fused_k(
    const ushort_t* __restrict__ Qp, const ushort_t* __restrict__ Ktc,
    const ushort_t* __restrict__ Qc, ushort_t* __restrict__ Kn,
    ushort_t* __restrict__ Qn) {
  const int b = blockIdx.x;
  __shared__ __align__(16) float S_lds[112 * SST];     // 16128 B
  __shared__ __align__(16) ushort_t Pq[32 * PQLD];     // 8704 B
  __shared__ __align__(16) ushort_t kts[NK * KTLD];    // 104000 B
  __shared__ __align__(16) ushort_t qts[NQ * HID];     // 30720 B
  const int tid = threadIdx.x;
  const int w = tid >> 6, lane = tid & 63;
  const ushort_t* ktg = Ktc + (size_t)b * NK * HID;
  const ushort_t* qtg = Qc + (size_t)b * NQ * HID;

  for (int e = tid; e < NK * 64; e += 512) {
    const int r = e >> 6, c16 = e & 63;
    gld_lds16(ktg + (size_t)r * HID + c16 * 8, kts + (size_t)r * KTLD + c16 * 8);
  }
  for (int e = tid; e < NQ * 64; e += 512) {
    const int r = e >> 6, c16 = e & 63;
    gld_lds16(qtg + (size_t)r * HID + c16 * 8, qts + (size_t)r * HID + c16 * 8);
  }
  __syncthreads();

  // ---- phase 1: S (waves 0-6) ----
  if (w < 7) {
    const int r = lane & 15, kq = lane >> 4;
    const ushort_t* qpb = Qp + (size_t)b * NQ * HID;
    const int rowA = w * 16 + r;
    const int rowA_c = (rowA < NK) ? rowA : (NK - 1);
    const int qr1 = (16 + r) < NQ ? (16 + r) : NQ - 1;
    f32x4 a0 = {0.f, 0.f, 0.f, 0.f}, a1 = {0.f, 0.f, 0.f, 0.f};
    for (int k0 = 0; k0 < HID; k0 += 32) {
      bf16x8 af = *(const bf16x8*)(kts + (size_t)rowA_c * KTLD + k0 + kq * 8);
      bf16x8 b0 = *(const bf16x8*)(qpb + (size_t)r * HID + k0 + kq * 8);
      bf16x8 b1 = *(const bf16x8*)(qpb + (size_t)qr1 * HID + k0 + kq * 8);
      a0 = __builtin_amdgcn_mfma_f32_16x16x32_bf16(af, b0, a0, 0, 0, 0);
      a1 = __builtin_amdgcn_mfma_f32_16x16x32_bf16(af, b1, a1, 0, 0, 0);
    }
    const int q0 = lane & 15, mb = (lane >> 4) * 4;
#pragma unroll
    for (int rr = 0; rr < 4; ++rr) {
      const int mA = w * 16 + mb + rr;
      if (mA < NK) {
        S_lds[mA * SST + q0] = a0[rr] * SCALE;
        if (q0 + 16 < NQ) S_lds[mA * SST + q0 + 16] = a1[rr] * SCALE;
      }
    }
  }
  __syncthreads();
  // ---- phase 2: softmaxes. threads 0-31: Pq side; threads 32-131: Pk read
  float e2[NQ];
  float inv2 = 0.f;
  const int kr2 = tid - 32;
  const bool do2b = (kr2 >= 0 && kr2 < NK);
  if (tid < NQ) {
    const int q = tid;
    float m = -1e30f;
    for (int kr = 0; kr < NK; ++kr) m = fmaxf(m, S_lds[kr * SST + q]);
    float s = 0.f;
    for (int kr = 0; kr < NK; ++kr) s += expf(S_lds[kr * SST + q] - m);
    float inv = 1.f / s;
    for (int kr = 0; kr < NK; ++kr)
      Pq[q * PQLD + kr] = f2bf(expf(S_lds[kr * SST + q] - m) * inv);
    for (int kr = NK; kr < 128; ++kr) Pq[q * PQLD + kr] = 0;
  } else if (tid < 32) {
    for (int kr = 0; kr < 128; ++kr) Pq[tid * PQLD + kr] = 0;
  } else if (do2b) {
    float m = -1e30f;
#pragma unroll
    for (int q = 0; q < NQ; ++q) m = fmaxf(m, S_lds[kr2 * SST + q]);
    float s = 0.f;
#pragma unroll
    for (int q = 0; q < NQ; ++q) {
      e2[q] = expf(S_lds[kr2 * SST + q] - m);
      s += e2[q];
    }
    inv2 = 1.f / s;
  }
  __syncthreads();
  // write Pk rows (bf16 overlay on S, row stride 72 u16)
  ushort_t* Pk = (ushort_t*)S_lds;
  if (do2b) {
    ushort_t* prow = Pk + kr2 * 72;
#pragma unroll
    for (int q = 0; q < NQ; ++q) prow[q] = f2bf(e2[q] * inv2);
    prow[30] = 0;
    prow[31] = 0;
  }
  __syncthreads();

  const int cl = lane & 15, g8 = (lane >> 4) * 8;
  // ---- phase 3: att_k = Pk @ qt + kt (MFMA, 1 K-step). wave owns 64 cols --
  {
    bf16x8 bk[4];
#pragma unroll
    for (int nt = 0; nt < 4; ++nt) {
      const int col = w * 64 + nt * 16 + cl;
      union { ushort_t u[8]; bf16x8 v; } pb;
#pragma unroll
      for (int j = 0; j < 8; ++j) {
        const int q = g8 + j;
        pb.u[j] = qts[(q < NQ ? q : NQ - 1) * HID + col];
      }
      bk[nt] = pb.v;
    }
    ushort_t* kout = Kn + (size_t)b * NK * HID;
#pragma unroll
    for (int mt = 0; mt < 7; ++mt) {
      bf16x8 af = *(const bf16x8*)(Pk + (mt * 16 + cl) * 72 + g8);
      f32x4 ac[4];
#pragma unroll
      for (int nt = 0; nt < 4; ++nt) {
        ac[nt] = (f32x4){0.f, 0.f, 0.f, 0.f};
        ac[nt] = __builtin_amdgcn_mfma_f32_16x16x32_bf16(af, bk[nt], ac[nt], 0, 0, 0);
      }
#pragma unroll
      for (int nt = 0; nt < 4; ++nt) {
        const int col = w * 64 + nt * 16 + cl;
#pragma unroll
        for (int r = 0; r < 4; ++r) {
          const int row = mt * 16 + (lane >> 4) * 4 + r;
          if (row < NK) {
            float v = ac[nt][r] + bf2f(kts[(size_t)row * KTLD + col]);
            kout[(size_t)row * HID + col] = f2bf(v);
          }
        }
      }
    }
  }
  // ---- phase 4: att_q = Pq @ kt + qt (MFMA, 4 K-steps) ----
  {
    f32x4 aq[2][4];
#pragma unroll
    for (int mt = 0; mt < 2; ++mt)
#pragma unroll
      for (int nt = 0; nt < 4; ++nt) aq[mt][nt] = (f32x4){0.f, 0.f, 0.f, 0.f};
#pragma unroll
    for (int ks = 0; ks < 4; ++ks) {
      bf16x8 bq[4];
#pragma unroll
      for (int nt = 0; nt < 4; ++nt) {
        const int col = w * 64 + nt * 16 + cl;
        union { ushort_t u[8]; bf16x8 v; } pb;
#pragma unroll
        for (int j = 0; j < 8; ++j) {
          const int kr = ks * 32 + g8 + j;
          pb.u[j] = kts[(size_t)(kr < NK ? kr : NK - 1) * KTLD + col];
        }
        bq[nt] = pb.v;
      }
#pragma unroll
      for (int mt = 0; mt < 2; ++mt) {
        bf16x8 af = *(const bf16x8*)(Pq + (mt * 16 + cl) * PQLD + ks * 32 + g8);
#pragma unroll
        for (int nt = 0; nt < 4; ++nt)
          aq[mt][nt] = __builtin_amdgcn_mfma_f32_16x16x32_bf16(af, bq[nt], aq[mt][nt], 0, 0, 0);
      }
    }
    ushort_t* qout = Qn + (size_t)b * NQ * HID;
#pragma unroll
    for (int mt = 0; mt < 2; ++mt)
#pragma unroll
      for (int nt = 0; nt < 4; ++nt) {
        const int col = w * 64 + nt * 16 + cl;
#pragma unroll
        for (int r = 0; r < 4; ++r) {
          const int row = mt * 16 + (lane >> 4) * 4 + r;
          if (row < NQ) {
            float v = aq[mt][nt][r] + bf2f(qts[(size_t)row * HID + col]);
            qout[(size_t)row * HID + col] = f2bf(v);
          }
        }
      }
  }
}

// ---------------- fused boundary: parallel row-norms ----------------
__global__ __launch_bounds__(512) void finale_k(
    const ushort_t* __restrict__ Kb, const ushort_t* __restrict__ Qb,
    ushort_t* __restrict__ lastb, const float* __restrict__ curv) {
  const int b = blockIdx.x, tid = threadIdx.x;
  const int w = tid >> 6, lane = tid & 63;
  const float c = curv[NLAYERS];
  const float Kc = 1.f / c, sqrtK = sqrtf(Kc);
  __shared__ float fsc[NK + NQ];
  __shared__ float fst[NK + NQ];
  const ushort_t* xkp = Kb + (size_t)b * NK * HID;
  const ushort_t* xqp = Qb + (size_t)b * NQ * HID;

  for (int r = w; r < NK + NQ; r += 8) {
    const ushort_t* row =
        (r < NK) ? (xkp + (size_t)r * HID) : (xqp + (size_t)(r - NK) * HID);
    bf16x8 v = *(const bf16x8*)(row + lane * 8);
    float ss = 0.f;
#pragma unroll
    for (int j = 0; j < 8; ++j) {
      float t = bf2f((unsigned short)v[j]);
      ss = fmaf(t, t, ss);
    }
    ss = waveReduceSum(ss);
    if (lane == 0) {
      float n = fmaxf(sqrtf(ss), 1e-15f);
      float f = sqrtK * sinhf(n / sqrtK) / n;
      fsc[r] = f;
      fst[r] = sqrtf(fmaxf(Kc + f * f * ss, 1e-7f));
    }
  }
  __syncthreads();

  float mk, mq;
  if (tid == 0) {
    float sk = 0.f, sq2 = 0.f;
    for (int r = 0; r < NK; ++r) sk += fst[r];
    for (int r = 0; r < NQ; ++r) sq2 += fst[NK + r];
    mk = sk;
    mq = sq2;
  } else {
    float sk = 0.f, sq2 = 0.f;
    for (int r = 0; r < NK; ++r)
      sk = fmaf(fsc[r], bf2f(xkp[(size_t)r * HID + tid]), sk);
    for (int r = 0; r < NQ; ++r)
      sq2 = fmaf(fsc[NK + r], bf2f(xqp[(size_t)r * HID + tid]), sq2);
    mk = sk;
    mq = sq2;
  }
  mk *= (1.f / NK);
  mq *= (1.f / NQ);

  float sq = ((tid == 0) ? 0.f : mk * mk) + mq * mq;
  float ssall = blockReduceSum512(sq);
  __shared__ float x0sh;
  if (tid == 0) x0sh = mk;
  __syncthreads();
  const float x0 = x0sh;
  const float n = fmaxf(sqrtf(ssall), 1e-15f);
  const float theta = fmaxf(x0 / sqrtK, 1.f + 1e-7f);
  const float rr = sqrtK * acoshf(theta) / n;
  ushort_t* ob = lastb + (size_t)b * 1024;
  ob[tid] = (tid == 0) ? (ushort_t)0 : f2bf(rr * mk);
  ob[512 + tid] = f2bf(rr * mq);
}

// ---------------- tail: 2-pass online log-softmax ----------------
__global__ __launch_bounds__(512) void logsoftmax_k(float* __restrict__ x) {
  const int b = blockIdx.x, tid = threadIdx.x;
  float4* row = (float4*)(x + (size_t)b * NANS);
  float m = -3.4e38f, s = 0.f;
  for (int i = tid; i < NANS / 4; i += 512) {
    float4 v = row[i];
    float lm = fmaxf(fmaxf(v.x, v.y), fmaxf(v.z, v.w));
    float nm = fmaxf(m, lm);
    s = s * expf(m - nm) + expf(v.x - nm) + expf(v.y - nm) +
        expf(v.z - nm) + expf(v.w - nm);
    m = nm;
  }
#pragma unroll
  for (int o = 32; o > 0; o >>= 1) {
    float mo = __shfl_xor(m, o);
    float so = __shfl_xor(s, o);
    float nm = fmaxf(m, mo);
    s = s * expf(m - nm) + so * expf(mo - nm);
    m = nm;
  }
  __shared__ float smm[8], sms[8];
  const int w = tid >> 6, lane = tid & 63;
  if (lane == 0) { smm[w] = m; sms[w] = s; }
  __syncthreads();
  float gm = smm[0], gs = sms[0];
#pragma unroll
  for (int i = 1; i < 8; ++i) {
    float nm = fmaxf(gm, smm[i]);
    gs = gs * expf(gm - nm) + sms[i] * expf(smm[i] - nm);
    gm = nm;
  }
  const float lse = gm + logf(gs);
  for (int i = tid; i < NANS / 4; i += 512) {
    float4 v = row[i];
    v.x -= lse; v.y -= lse; v.z -= lse; v.w -= lse;
    row[i] = v;
  }
}

// ---------------- launch ----------------
extern "C" void kernel_launch(void* const* d_in, const int* in_sizes, int n_in,
                              void* d_out, int out_size, void* d_ws, size_t ws_size,
                              hipStream_t stream) {
  const int* qid = (const int*)d_in[0];
  const int* kid = (const int*)d_in[1];
  const float* emb = (const float*)d_in[2];
  const float* q2h_w = (const float*)d_in[3];
  const float* q2h_b = (const float*)d_in[4];
  const float* k2h_w = (const float*)d_in[5];
  const float* k2h_b = (const float*)d_in[6];
  const float* Wk = (const float*)d_in[7];
  const float* Wq = (const float*)d_in[8];
  const float* curv = (const float*)d_in[9];
  const float* p1w = (const float*)d_in[10];
  const float* p1b = (const float*)d_in[11];
  const float* p2w = (const float*)d_in[12];
  const float* p2b = (const float*)d_in[13];
  const float* glove = (const float*)d_in[14];
  float* out = (float*)d_out;

  // ---- workspace layout (all bf16) ----
  ushort_t* u = (ushort_t*)d_ws;
  ushort_t* Ks0 = u;
  ushort_t* Ks1 = Ks0 + (size_t)MKT * HID;
  ushort_t* Qs0 = Ks1 + (size_t)MKT * HID;
  ushort_t* Qs1 = Qs0 + (size_t)MQT * HID;
  ushort_t* Qps = Qs1 + (size_t)MQT * HID;
  ushort_t* gq = Qps + (size_t)MQT * HID;
  ushort_t* gk = gq + (size_t)MQT * KP;
  ushort_t* q2h_wt = gk + (size_t)MKT * KP;
  ushort_t* k2h_wt = q2h_wt + (size_t)HID * KP;
  ushort_t* Wkr = k2h_wt + (size_t)HID * KP;
  ushort_t* Wqr = Wkr + (size_t)NLAYERS * HID * HID;
  ushort_t* Mb = Wqr + (size_t)NLAYERS * HID * HID;
  ushort_t* p1wt = Mb + (size_t)NLAYERS * HID * HID;
  ushort_t* p2wt = p1wt + (size_t)HID * 1024;
  ushort_t* lastb = p2wt + (size_t)NOUTP * HID;
  ushort_t* h1b = lastb + (size_t)BATCH * 1024;
  ushort_t* o2b = h1b + (size_t)BATCH * HID;
  ushort_t* gsw = o2b + (size_t)BATCH * NOUTP;

  // ---- pre-casts ----
  gather_all_k<<<MQT + MKT, 256, 0, stream>>>(qid, kid, emb, gq, gk);
  tcast4_k<<<dim3(16, 32, 4), 256, 0, stream>>>(
      q2h_w, k2h_w, p1w, p2w, q2h_wt, k2h_wt, p1wt, p2wt);
  castrows_k<<<6 * HID, 128, 0, stream>>>(Wk, Wq, Wkr, Wqr);
  gcast_swz_k<<<dim3(NTG, 250), 256, 0, stream>>>(glove, gsw);

  // ---- M_i = Wk_i @ Wq_i^T (bf16 out), batched over z ----
  mfma_gemm2<0, 0, 0, 1, 0, 0><<<dim3(HID / 128, HID / 128, NLAYERS), 256, 0, stream>>>(
      Wkr, Wqr, nullptr, nullptr, Mb, HID / 128,
      Wkr, Wqr, nullptr, nullptr, Mb,
      (size_t)HID * HID, (size_t)HID * HID, (size_t)HID * HID, HID, HID, HID);

  // ---- input projections (merged q+k), fused proj_tan0, bf16 out ----
  mfma_gemm2<0, 1, 0, 1, 1, 0><<<dim3(HID / 128, MQT / 128 + MKT / 128), 256, 0, stream>>>(
      gq, q2h_wt, q2h_b, nullptr, Qs0, MQT / 128,
      gk, k2h_wt, k2h_b, nullptr, Ks0, 0, 0, 0, HID, KP, HID);

  // ---- layers in tangent space ----
  ushort_t* Kc = Ks0;
  ushort_t* Kn = Ks1;
  ushort_t* Qc = Qs0;
  ushort_t* Qn = Qs1;
  for (int i = 0; i < NLAYERS; ++i) {
    mfma_gemm2<0, 0, 0, 1, 0, 0><<<dim3(HID / 128, MQT / 128), 256, 0, stream>>>(
        Qc, Mb + (size_t)i * HID * HID, nullptr, nullptr, Qps, MQT / 128,
        Qc, Mb + (size_t)i * HID * HID, nullptr, nullptr, Qps,
        0, 0, 0, HID, HID, HID);
    att_fused_k<<<BATCH, 512, 0, stream>>>(Qps, Kc, Qc, Kn, Qn);
    ushort_t* t1 = Kc; Kc = Kn; Kn = t1;
    ushort_t* t2 = Qc; Qc = Qn; Qn = t2;
  }

  // ---- fused boundary (expproj + mean + logmap) -> lastb bf16 ----
  finale_k<<<BATCH, 512, 0, stream>>>(Kc, Qc, lastb, curv);

  // ---- head (all MFMA bf16) ----
  mfma_gemm2<0, 1, 0, 1, 0, 1><<<dim3(HID / 128, BATCH / 128), 256, 0, stream>>>(
      lastb, p1wt, p1b, nullptr, h1b, BATCH / 128,
      lastb, p1wt, p1b, nullptr, h1b, 0, 0, 0, HID, 1024, HID);
  mfma_gemm2<0, 1, 0, 1, 0, 0><<<dim3(NOUTP / 128, BATCH / 128), 256, 0, stream>>>(
      h1b, p2wt, p2b, nullptr, o2b, BATCH / 128,
      h1b, p2wt, p2b, nullptr, o2b, 0, 0, 0, NOUTP, HID, NOUT);
  // sim: B = swizzled glove bf16
  mfma_gemm2<1, 0, 1, 0, 0, 0><<<dim3(NANS / 128, BATCH / 128), 256, 0, stream>>>(
      o2b, gsw, nullptr, out, nullptr, BATCH / 128,
      o2b, gsw, nullptr, out, nullptr, 0, 0, 0, NANS, NOUTP, NANS);
  logsoftmax_k<<<BATCH, 512, 0, stream>>>(out);
}